// Round 1
// baseline (1545.377 us; speedup 1.0000x reference)
//
#include <hip/hip_runtime.h>

#define N_NODES 50000
#define N_EDGES 1600000
#define ETOT (N_EDGES + N_NODES)   // 1,650,000 (self-loops appended)
#define F_IN 2304
#define HD 64    // H1*D1
#define H1 8
#define D1 8
#define NC 5

// ---------- helpers ----------
__device__ __forceinline__ unsigned enc_f(float f) {
    unsigned u = __float_as_uint(f);
    return (u & 0x80000000u) ? ~u : (u | 0x80000000u);
}
__device__ __forceinline__ float dec_f(unsigned u) {
    return __uint_as_float((u & 0x80000000u) ? (u & 0x7FFFFFFFu) : ~u);
}
__device__ __forceinline__ float lrelu(float x) { return x > 0.f ? x : 0.2f * x; }

__device__ __forceinline__ void edge_sd(const int* __restrict__ ei, int e, int& s, int& t) {
    if (e < N_EDGES) { s = ei[e]; t = ei[N_EDGES + e]; }
    else { s = e - N_EDGES; t = s; }
}

// ---------- init ----------
__global__ void init_m_kernel(unsigned* __restrict__ m1, unsigned* __restrict__ m2) {
    int i = blockIdx.x * blockDim.x + threadIdx.x;
    if (i < N_NODES * H1) m1[i] = 0x007FFFFFu;   // enc(-inf)
    if (i < N_NODES)      m2[i] = 0x007FFFFFu;
}

// ---------- layer 1 projection: h1p = x @ W1  (50000 x 2304 x 64) ----------
__global__ __launch_bounds__(256) void gemm1_kernel(const float* __restrict__ x,
                                                    const float* __restrict__ W,
                                                    float* __restrict__ h) {
    __shared__ float As[64][33];
    __shared__ float Bs[32][64];
    int m0 = blockIdx.x * 64;
    int t = threadIdx.x;
    int tr = t >> 4, tc = t & 15;
    float acc[4][4] = {};
    for (int k0 = 0; k0 < F_IN; k0 += 32) {
        #pragma unroll
        for (int i = 0; i < 8; i++) {           // A tile 64x32
            int idx = t + i * 256;
            int r = idx >> 5, k = idx & 31;
            int gr = m0 + r;
            As[r][k] = (gr < N_NODES) ? x[(long)gr * F_IN + k0 + k] : 0.f;
        }
        #pragma unroll
        for (int i = 0; i < 8; i++) {           // B tile 32x64
            int idx = t + i * 256;
            int k = idx >> 6, c = idx & 63;
            Bs[k][c] = W[(k0 + k) * HD + c];
        }
        __syncthreads();
        #pragma unroll
        for (int kk = 0; kk < 32; kk++) {
            float a[4], b[4];
            #pragma unroll
            for (int i = 0; i < 4; i++) a[i] = As[tr * 4 + i][kk];
            #pragma unroll
            for (int j = 0; j < 4; j++) b[j] = Bs[kk][tc * 4 + j];
            #pragma unroll
            for (int i = 0; i < 4; i++)
                #pragma unroll
                for (int j = 0; j < 4; j++)
                    acc[i][j] += a[i] * b[j];
        }
        __syncthreads();
    }
    #pragma unroll
    for (int i = 0; i < 4; i++) {
        int gr = m0 + tr * 4 + i;
        if (gr < N_NODES) {
            #pragma unroll
            for (int j = 0; j < 4; j++)
                h[(long)gr * HD + tc * 4 + j] = acc[i][j];
        }
    }
}

// ---------- per-node attention terms (layer 1) ----------
__global__ void att1_kernel(const float* __restrict__ h,
                            const float* __restrict__ asrc_w, const float* __restrict__ adst_w,
                            float* __restrict__ a_src, float* __restrict__ a_dst) {
    int idx = blockIdx.x * blockDim.x + threadIdx.x;   // n*8 + head
    if (idx >= N_NODES * H1) return;
    int n = idx >> 3, hh = idx & 7;
    float s = 0.f, dd = 0.f;
    #pragma unroll
    for (int d = 0; d < 8; d++) {
        float v = h[n * 64 + hh * 8 + d];
        s  += v * asrc_w[hh * 8 + d];
        dd += v * adst_w[hh * 8 + d];
    }
    a_src[idx] = s;
    a_dst[idx] = dd;
}

// ---------- layer-1 edge passes ----------
__global__ void edgeA1(const int* __restrict__ ei, const float* __restrict__ a_src,
                       const float* __restrict__ a_dst, unsigned* __restrict__ m1) {
    int idx = blockIdx.x * blockDim.x + threadIdx.x;   // e*8 + head
    if (idx >= ETOT * H1) return;
    int e = idx >> 3, hh = idx & 7;
    int s, t; edge_sd(ei, e, s, t);
    float lg = lrelu(a_src[s * 8 + hh] + a_dst[t * 8 + hh]);
    atomicMax(&m1[t * 8 + hh], enc_f(lg));
}

__global__ void edgeB1(const int* __restrict__ ei, const float* __restrict__ a_src,
                       const float* __restrict__ a_dst, const unsigned* __restrict__ m1,
                       float* __restrict__ z1) {
    int idx = blockIdx.x * blockDim.x + threadIdx.x;
    if (idx >= ETOT * H1) return;
    int e = idx >> 3, hh = idx & 7;
    int s, t; edge_sd(ei, e, s, t);
    float lg = lrelu(a_src[s * 8 + hh] + a_dst[t * 8 + hh]);
    float p = expf(lg - dec_f(m1[t * 8 + hh]));
    atomicAdd(&z1[t * 8 + hh], p);
}

__global__ void edgeC1(const int* __restrict__ ei, const float* __restrict__ a_src,
                       const float* __restrict__ a_dst, const unsigned* __restrict__ m1,
                       const float* __restrict__ z1, const float* __restrict__ h1p,
                       float* __restrict__ out1) {
    long long tid = (long long)blockIdx.x * blockDim.x + threadIdx.x;
    int e = (int)(tid >> 6);
    if (e >= ETOT) return;
    int k = (int)tid & 63;
    int hh = k >> 3;
    int s, t; edge_sd(ei, e, s, t);
    float lg = lrelu(a_src[s * 8 + hh] + a_dst[t * 8 + hh]);
    float p = expf(lg - dec_f(m1[t * 8 + hh]));
    float alpha = p / (z1[t * 8 + hh] + 1e-16f);
    atomicAdd(&out1[(long)t * 64 + k], alpha * h1p[(long)s * 64 + k]);
}

// ---------- layer-2 projection (+b1 fused) + attention terms ----------
__global__ __launch_bounds__(256) void proj2_kernel(const float* __restrict__ out1,
                                                    const float* __restrict__ b1,
                                                    const float* __restrict__ W2,
                                                    const float* __restrict__ asrc2_w,
                                                    const float* __restrict__ adst2_w,
                                                    float* __restrict__ h2p,
                                                    float* __restrict__ a_src2,
                                                    float* __restrict__ a_dst2) {
    int gtid = blockIdx.x * blockDim.x + threadIdx.x;
    int n = gtid >> 6;
    int lane = threadIdx.x & 63;
    if (n >= N_NODES) return;
    float v = out1[(long)n * 64 + lane] + b1[lane];
    float part[NC];
    #pragma unroll
    for (int c = 0; c < NC; c++) part[c] = v * W2[lane * NC + c];
    #pragma unroll
    for (int off = 32; off >= 1; off >>= 1)
        #pragma unroll
        for (int c = 0; c < NC; c++) part[c] += __shfl_xor(part[c], off, 64);
    if (lane == 0) {
        float as = 0.f, ad = 0.f;
        #pragma unroll
        for (int c = 0; c < NC; c++) {
            h2p[n * NC + c] = part[c];
            as += part[c] * asrc2_w[c];
            ad += part[c] * adst2_w[c];
        }
        a_src2[n] = as;
        a_dst2[n] = ad;
    }
}

// ---------- layer-2 edge passes (1 head, 5 dims) ----------
__global__ void edgeA2(const int* __restrict__ ei, const float* __restrict__ a_src2,
                       const float* __restrict__ a_dst2, unsigned* __restrict__ m2) {
    int e = blockIdx.x * blockDim.x + threadIdx.x;
    if (e >= ETOT) return;
    int s, t; edge_sd(ei, e, s, t);
    atomicMax(&m2[t], enc_f(lrelu(a_src2[s] + a_dst2[t])));
}

__global__ void edgeB2(const int* __restrict__ ei, const float* __restrict__ a_src2,
                       const float* __restrict__ a_dst2, const unsigned* __restrict__ m2,
                       float* __restrict__ z2) {
    int e = blockIdx.x * blockDim.x + threadIdx.x;
    if (e >= ETOT) return;
    int s, t; edge_sd(ei, e, s, t);
    float lg = lrelu(a_src2[s] + a_dst2[t]);
    atomicAdd(&z2[t], expf(lg - dec_f(m2[t])));
}

__global__ void edgeC2(const int* __restrict__ ei, const float* __restrict__ a_src2,
                       const float* __restrict__ a_dst2, const unsigned* __restrict__ m2,
                       const float* __restrict__ z2, const float* __restrict__ h2p,
                       float* __restrict__ out2) {
    int e = blockIdx.x * blockDim.x + threadIdx.x;
    if (e >= ETOT) return;
    int s, t; edge_sd(ei, e, s, t);
    float lg = lrelu(a_src2[s] + a_dst2[t]);
    float p = expf(lg - dec_f(m2[t]));
    float alpha = p / (z2[t] + 1e-16f);
    #pragma unroll
    for (int c = 0; c < NC; c++)
        atomicAdd(&out2[t * NC + c], alpha * h2p[s * NC + c]);
}

// ---------- final: +b2, log_softmax ----------
__global__ void final_kernel(const float* __restrict__ out2, const float* __restrict__ b2,
                             float* __restrict__ y) {
    int n = blockIdx.x * blockDim.x + threadIdx.x;
    if (n >= N_NODES) return;
    float l[NC];
    float mx = -3.4e38f;
    #pragma unroll
    for (int c = 0; c < NC; c++) {
        l[c] = out2[n * NC + c] + b2[c];
        mx = fmaxf(mx, l[c]);
    }
    float ssum = 0.f;
    #pragma unroll
    for (int c = 0; c < NC; c++) ssum += expf(l[c] - mx);
    float lse = logf(ssum);
    #pragma unroll
    for (int c = 0; c < NC; c++) y[n * NC + c] = l[c] - mx - lse;
}

extern "C" void kernel_launch(void* const* d_in, const int* in_sizes, int n_in,
                              void* d_out, int out_size, void* d_ws, size_t ws_size,
                              hipStream_t stream) {
    const float* x        = (const float*)d_in[0];
    const int*   ei       = (const int*)d_in[1];
    const float* W1       = (const float*)d_in[2];
    const float* att_src1 = (const float*)d_in[3];
    const float* att_dst1 = (const float*)d_in[4];
    const float* b1       = (const float*)d_in[5];
    const float* W2       = (const float*)d_in[6];
    const float* att_src2 = (const float*)d_in[7];
    const float* att_dst2 = (const float*)d_in[8];
    const float* b2       = (const float*)d_in[9];
    float* y = (float*)d_out;

    float* ws      = (float*)d_ws;
    float* h1p     = ws;                         // N*64
    float* a_src1  = h1p + (long)N_NODES * 64;   // N*8
    float* a_dst1  = a_src1 + N_NODES * 8;       // N*8
    unsigned* m1   = (unsigned*)(a_dst1 + N_NODES * 8);  // N*8
    float* z1      = (float*)(m1 + N_NODES * 8); // N*8
    float* out1    = z1 + N_NODES * 8;           // N*64
    float* h2p     = out1 + (long)N_NODES * 64;  // N*5
    float* a_src2  = h2p + N_NODES * NC;         // N
    float* a_dst2  = a_src2 + N_NODES;           // N
    unsigned* m2   = (unsigned*)(a_dst2 + N_NODES); // N
    float* z2      = (float*)(m2 + N_NODES);     // N
    float* out2    = z2 + N_NODES;               // N*5

    // re-init accumulators every call (graph-safe)
    hipMemsetAsync(z1,   0, N_NODES * 8 * sizeof(float), stream);
    hipMemsetAsync(out1, 0, (size_t)N_NODES * 64 * sizeof(float), stream);
    hipMemsetAsync(z2,   0, N_NODES * sizeof(float), stream);
    hipMemsetAsync(out2, 0, N_NODES * NC * sizeof(float), stream);
    init_m_kernel<<<(N_NODES * 8 + 255) / 256, 256, 0, stream>>>(m1, m2);

    // layer 1
    gemm1_kernel<<<(N_NODES + 63) / 64, 256, 0, stream>>>(x, W1, h1p);
    att1_kernel<<<(N_NODES * 8 + 255) / 256, 256, 0, stream>>>(h1p, att_src1, att_dst1, a_src1, a_dst1);
    edgeA1<<<(ETOT * 8 + 255) / 256, 256, 0, stream>>>(ei, a_src1, a_dst1, m1);
    edgeB1<<<(ETOT * 8 + 255) / 256, 256, 0, stream>>>(ei, a_src1, a_dst1, m1, z1);
    edgeC1<<<(int)(((long long)ETOT * 64 + 255) / 256), 256, 0, stream>>>(ei, a_src1, a_dst1, m1, z1, h1p, out1);

    // layer 2
    proj2_kernel<<<(N_NODES * 64 + 255) / 256, 256, 0, stream>>>(out1, b1, W2, att_src2, att_dst2, h2p, a_src2, a_dst2);
    edgeA2<<<(ETOT + 255) / 256, 256, 0, stream>>>(ei, a_src2, a_dst2, m2);
    edgeB2<<<(ETOT + 255) / 256, 256, 0, stream>>>(ei, a_src2, a_dst2, m2, z2);
    edgeC2<<<(ETOT + 255) / 256, 256, 0, stream>>>(ei, a_src2, a_dst2, m2, z2, h2p, out2);

    final_kernel<<<(N_NODES + 255) / 256, 256, 0, stream>>>(out2, b2, y);
}

// Round 2
// 652.361 us; speedup vs baseline: 2.3689x; 2.3689x over previous
//
#include <hip/hip_runtime.h>

#define N_NODES 50000
#define N_EDGES 1600000
#define ETOT (N_EDGES + N_NODES)   // 1,650,000 (self-loops appended)
#define F_IN 2304
#define HD 64    // H1*D1
#define H1 8
#define D1 8
#define NC 5
#define NB_SCAN ((N_NODES + 255) / 256)   // 196

__device__ __forceinline__ float lrelu(float x) { return x > 0.f ? x : 0.2f * x; }

__device__ __forceinline__ void edge_sd(const int* __restrict__ ei, int e, int& s, int& t) {
    if (e < N_EDGES) { s = ei[e]; t = ei[N_EDGES + e]; }
    else { s = e - N_EDGES; t = s; }
}

// ================= CSR build =================
__global__ void hist_kernel(const int* __restrict__ ei, unsigned* __restrict__ deg) {
    int e = blockIdx.x * blockDim.x + threadIdx.x;
    if (e >= ETOT) return;
    int s, t; edge_sd(ei, e, s, t);
    atomicAdd(&deg[t], 1u);
}

__global__ void scan_block_kernel(const unsigned* __restrict__ deg,
                                  unsigned* __restrict__ rowptr,
                                  unsigned* __restrict__ bsum) {
    __shared__ unsigned sm[256];
    int i = blockIdx.x * 256 + threadIdx.x;
    unsigned v = (i < N_NODES) ? deg[i] : 0u;
    sm[threadIdx.x] = v;
    __syncthreads();
    #pragma unroll
    for (int off = 1; off < 256; off <<= 1) {
        unsigned u = (threadIdx.x >= off) ? sm[threadIdx.x - off] : 0u;
        __syncthreads();
        sm[threadIdx.x] += u;
        __syncthreads();
    }
    if (i < N_NODES) rowptr[i] = sm[threadIdx.x] - v;   // exclusive
    if (threadIdx.x == 255) bsum[blockIdx.x] = sm[255];
}

__global__ void scan_top_kernel(unsigned* __restrict__ bsum, unsigned* __restrict__ boff) {
    __shared__ unsigned sm[256];
    int i = threadIdx.x;
    unsigned v = (i < NB_SCAN) ? bsum[i] : 0u;
    sm[i] = v;
    __syncthreads();
    #pragma unroll
    for (int off = 1; off < 256; off <<= 1) {
        unsigned u = (i >= off) ? sm[i - off] : 0u;
        __syncthreads();
        sm[i] += u;
        __syncthreads();
    }
    if (i < NB_SCAN) boff[i] = sm[i] - v;   // exclusive
}

__global__ void scan_add_kernel(unsigned* __restrict__ rowptr, const unsigned* __restrict__ boff) {
    int i = blockIdx.x * 256 + threadIdx.x;
    if (i < N_NODES) rowptr[i] += boff[blockIdx.x];
    if (i == 0) rowptr[N_NODES] = ETOT;
}

__global__ void fill_kernel(const int* __restrict__ ei, const unsigned* __restrict__ rowptr,
                            unsigned* __restrict__ cursor, int* __restrict__ col) {
    int e = blockIdx.x * blockDim.x + threadIdx.x;
    if (e >= ETOT) return;
    int s, t; edge_sd(ei, e, s, t);
    unsigned pos = atomicAdd(&cursor[t], 1u);
    col[rowptr[t] + pos] = s;
}

// ============ layer 1 projection: h1p = x @ W1 (50000 x 2304 x 64) ============
__global__ __launch_bounds__(256) void gemm1_kernel(const float* __restrict__ x,
                                                    const float* __restrict__ W,
                                                    float* __restrict__ h) {
    __shared__ float As[32][68];   // k-major: As[k][row], pad 64->68
    __shared__ float Bs[32][68];   // Bs[k][col], pad 64->68
    int m0 = blockIdx.x * 64;
    int t = threadIdx.x;
    int tr = t >> 4, tc = t & 15;
    float acc[4][4] = {};
    for (int k0 = 0; k0 < F_IN; k0 += 32) {
        // A tile: 64 rows x 32 k, float4 loads, transpose into k-major LDS
        #pragma unroll
        for (int i = 0; i < 2; i++) {
            int idx = t + i * 256;          // 0..511 float4 slots
            int r = idx >> 3, k4 = idx & 7; // 8 float4 per row
            int gr = m0 + r;
            float4 v = make_float4(0.f, 0.f, 0.f, 0.f);
            if (gr < N_NODES)
                v = *reinterpret_cast<const float4*>(&x[(long)gr * F_IN + k0 + k4 * 4]);
            As[k4 * 4 + 0][r] = v.x;
            As[k4 * 4 + 1][r] = v.y;
            As[k4 * 4 + 2][r] = v.z;
            As[k4 * 4 + 3][r] = v.w;
        }
        // B tile: 32 k x 64 cols, float4 loads
        #pragma unroll
        for (int i = 0; i < 2; i++) {
            int idx = t + i * 256;
            int kr = idx >> 4, c4 = idx & 15;  // 16 float4 per k-row
            float4 v = *reinterpret_cast<const float4*>(&W[(k0 + kr) * HD + c4 * 4]);
            *reinterpret_cast<float4*>(&Bs[kr][c4 * 4]) = v;
        }
        __syncthreads();
        #pragma unroll
        for (int kk = 0; kk < 32; kk++) {
            float4 av = *reinterpret_cast<const float4*>(&As[kk][tr * 4]);
            float4 bv = *reinterpret_cast<const float4*>(&Bs[kk][tc * 4]);
            float a[4] = {av.x, av.y, av.z, av.w};
            float b[4] = {bv.x, bv.y, bv.z, bv.w};
            #pragma unroll
            for (int i = 0; i < 4; i++)
                #pragma unroll
                for (int j = 0; j < 4; j++)
                    acc[i][j] += a[i] * b[j];
        }
        __syncthreads();
    }
    #pragma unroll
    for (int i = 0; i < 4; i++) {
        int gr = m0 + tr * 4 + i;
        if (gr < N_NODES) {
            float4 v = make_float4(acc[i][0], acc[i][1], acc[i][2], acc[i][3]);
            *reinterpret_cast<float4*>(&h[(long)gr * HD + tc * 4]) = v;
        }
    }
}

// ---------- per-node attention terms (layer 1) ----------
__global__ void att1_kernel(const float* __restrict__ h,
                            const float* __restrict__ asrc_w, const float* __restrict__ adst_w,
                            float* __restrict__ a_src, float* __restrict__ a_dst) {
    int idx = blockIdx.x * blockDim.x + threadIdx.x;   // n*8 + head
    if (idx >= N_NODES * H1) return;
    int n = idx >> 3, hh = idx & 7;
    float s = 0.f, dd = 0.f;
    #pragma unroll
    for (int d = 0; d < 8; d++) {
        float v = h[(long)n * 64 + hh * 8 + d];
        s  += v * asrc_w[hh * 8 + d];
        dd += v * adst_w[hh * 8 + d];
    }
    a_src[idx] = s;
    a_dst[idx] = dd;
}

// ---------- layer-1 fused segment softmax + aggregation (wave per node) ----------
__global__ __launch_bounds__(256) void agg1_kernel(const unsigned* __restrict__ rowptr,
                                                   const int* __restrict__ col,
                                                   const float* __restrict__ a_src,
                                                   const float* __restrict__ a_dst,
                                                   const float* __restrict__ h,
                                                   float* __restrict__ out) {
    int n = blockIdx.x * 4 + (threadIdx.x >> 6);
    if (n >= N_NODES) return;
    int k = threadIdx.x & 63;
    int hh = k >> 3;
    float ad = a_dst[n * 8 + hh];
    int r0 = rowptr[n], r1 = rowptr[n + 1];
    float acc = 0.f, z = 0.f;
    for (int e = r0; e < r1; ++e) {
        int s = col[e];
        float p = __expf(lrelu(a_src[s * 8 + hh] + ad));
        z += p;
        acc += p * h[(long)s * 64 + k];
    }
    out[(long)n * 64 + k] = acc / (z + 1e-16f);
}

// ---------- layer-2 projection (+b1 fused) + attention terms ----------
__global__ __launch_bounds__(256) void proj2_kernel(const float* __restrict__ out1,
                                                    const float* __restrict__ b1,
                                                    const float* __restrict__ W2,
                                                    const float* __restrict__ asrc2_w,
                                                    const float* __restrict__ adst2_w,
                                                    float* __restrict__ h2p,
                                                    float* __restrict__ a_src2,
                                                    float* __restrict__ a_dst2) {
    int gtid = blockIdx.x * blockDim.x + threadIdx.x;
    int n = gtid >> 6;
    int lane = threadIdx.x & 63;
    if (n >= N_NODES) return;
    float v = out1[(long)n * 64 + lane] + b1[lane];
    float part[NC];
    #pragma unroll
    for (int c = 0; c < NC; c++) part[c] = v * W2[lane * NC + c];
    #pragma unroll
    for (int off = 32; off >= 1; off >>= 1)
        #pragma unroll
        for (int c = 0; c < NC; c++) part[c] += __shfl_xor(part[c], off, 64);
    if (lane == 0) {
        float as = 0.f, ad = 0.f;
        #pragma unroll
        for (int c = 0; c < NC; c++) {
            h2p[n * NC + c] = part[c];
            as += part[c] * asrc2_w[c];
            ad += part[c] * adst2_w[c];
        }
        a_src2[n] = as;
        a_dst2[n] = ad;
    }
}

// ---------- layer-2 fused softmax+agg+bias+log_softmax (thread per node) ----------
__global__ void agg2_kernel(const unsigned* __restrict__ rowptr, const int* __restrict__ col,
                            const float* __restrict__ a_src2, const float* __restrict__ a_dst2,
                            const float* __restrict__ h2p, const float* __restrict__ b2,
                            float* __restrict__ y) {
    int n = blockIdx.x * blockDim.x + threadIdx.x;
    if (n >= N_NODES) return;
    float ad = a_dst2[n];
    int r0 = rowptr[n], r1 = rowptr[n + 1];
    float acc[NC] = {};
    float z = 0.f;
    for (int e = r0; e < r1; ++e) {
        int s = col[e];
        float p = __expf(lrelu(a_src2[s] + ad));
        z += p;
        #pragma unroll
        for (int c = 0; c < NC; c++) acc[c] += p * h2p[s * NC + c];
    }
    float inv = 1.f / (z + 1e-16f);
    float l[NC], mx = -3.4e38f;
    #pragma unroll
    for (int c = 0; c < NC; c++) {
        l[c] = acc[c] * inv + b2[c];
        mx = fmaxf(mx, l[c]);
    }
    float ssum = 0.f;
    #pragma unroll
    for (int c = 0; c < NC; c++) ssum += __expf(l[c] - mx);
    float lse = __logf(ssum);
    #pragma unroll
    for (int c = 0; c < NC; c++) y[n * NC + c] = l[c] - mx - lse;
}

extern "C" void kernel_launch(void* const* d_in, const int* in_sizes, int n_in,
                              void* d_out, int out_size, void* d_ws, size_t ws_size,
                              hipStream_t stream) {
    const float* x        = (const float*)d_in[0];
    const int*   ei       = (const int*)d_in[1];
    const float* W1       = (const float*)d_in[2];
    const float* att_src1 = (const float*)d_in[3];
    const float* att_dst1 = (const float*)d_in[4];
    const float* b1       = (const float*)d_in[5];
    const float* W2       = (const float*)d_in[6];
    const float* att_src2 = (const float*)d_in[7];
    const float* att_dst2 = (const float*)d_in[8];
    const float* b2       = (const float*)d_in[9];
    float* y = (float*)d_out;

    // workspace layout
    float* ws      = (float*)d_ws;
    float* h1p     = ws;                                  // N*64
    float* a_src1  = h1p + (long)N_NODES * 64;            // N*8
    float* a_dst1  = a_src1 + N_NODES * 8;                // N*8
    float* out1    = a_dst1 + N_NODES * 8;                // N*64
    float* h2p     = out1 + (long)N_NODES * 64;           // N*5
    float* a_src2  = h2p + N_NODES * NC;                  // N
    float* a_dst2  = a_src2 + N_NODES;                    // N
    unsigned* deg    = (unsigned*)(a_dst2 + N_NODES);     // N
    unsigned* cursor = deg + N_NODES;                     // N
    unsigned* rowptr = cursor + N_NODES;                  // N+1
    unsigned* bsum   = rowptr + N_NODES + 1;              // 256
    unsigned* boff   = bsum + 256;                        // 256
    int*      col    = (int*)(boff + 256);                // ETOT

    // ---- CSR build (per call, graph-safe) ----
    hipMemsetAsync(deg,    0, N_NODES * sizeof(unsigned), stream);
    hipMemsetAsync(cursor, 0, N_NODES * sizeof(unsigned), stream);
    hist_kernel<<<(ETOT + 255) / 256, 256, 0, stream>>>(ei, deg);
    scan_block_kernel<<<NB_SCAN, 256, 0, stream>>>(deg, rowptr, bsum);
    scan_top_kernel<<<1, 256, 0, stream>>>(bsum, boff);
    scan_add_kernel<<<NB_SCAN, 256, 0, stream>>>(rowptr, boff);
    fill_kernel<<<(ETOT + 255) / 256, 256, 0, stream>>>(ei, rowptr, cursor, col);

    // ---- layer 1 ----
    gemm1_kernel<<<(N_NODES + 63) / 64, 256, 0, stream>>>(x, W1, h1p);
    att1_kernel<<<(N_NODES * 8 + 255) / 256, 256, 0, stream>>>(h1p, att_src1, att_dst1, a_src1, a_dst1);
    agg1_kernel<<<(N_NODES + 3) / 4, 256, 0, stream>>>(rowptr, col, a_src1, a_dst1, h1p, out1);

    // ---- layer 2 ----
    proj2_kernel<<<(N_NODES * 64 + 255) / 256, 256, 0, stream>>>(out1, b1, W2, att_src2, att_dst2, h2p, a_src2, a_dst2);
    agg2_kernel<<<(N_NODES + 255) / 256, 256, 0, stream>>>(rowptr, col, a_src2, a_dst2, h2p, b2, y);
}

// Round 3
// 539.260 us; speedup vs baseline: 2.8657x; 1.2097x over previous
//
#include <hip/hip_runtime.h>

#define N_NODES 50000
#define N_EDGES 1600000
#define ETOT (N_EDGES + N_NODES)   // 1,650,000 (self-loops appended)
#define F_IN 2304
#define HD 64    // H1*D1
#define H1 8
#define D1 8
#define NC 5
#define NB_SCAN ((N_NODES + 255) / 256)   // 196
#define KB (F_IN / 32)                    // 72 K-blocks
#define NTILE (N_NODES / 16)              // 3125 wave tiles

typedef __attribute__((ext_vector_type(8))) short short8v;
typedef __attribute__((ext_vector_type(4))) float f32x4;

__device__ __forceinline__ float lrelu(float x) { return x > 0.f ? x : 0.2f * x; }

__device__ __forceinline__ short f2bf(float f) {   // RNE fp32->bf16
    unsigned u = __float_as_uint(f);
    u += 0x7fffu + ((u >> 16) & 1u);
    return (short)(u >> 16);
}

__device__ __forceinline__ void edge_sd(const int* __restrict__ ei, int e, int& s, int& t) {
    if (e < N_EDGES) { s = ei[e]; t = ei[N_EDGES + e]; }
    else { s = e - N_EDGES; t = s; }
}

// ================= CSR build =================
__global__ void hist_kernel(const int* __restrict__ ei, unsigned* __restrict__ deg) {
    int e = blockIdx.x * blockDim.x + threadIdx.x;
    if (e >= ETOT) return;
    int s, t; edge_sd(ei, e, s, t);
    atomicAdd(&deg[t], 1u);
}

__global__ void scan_block_kernel(const unsigned* __restrict__ deg,
                                  unsigned* __restrict__ rowptr,
                                  unsigned* __restrict__ bsum) {
    __shared__ unsigned sm[256];
    int i = blockIdx.x * 256 + threadIdx.x;
    unsigned v = (i < N_NODES) ? deg[i] : 0u;
    sm[threadIdx.x] = v;
    __syncthreads();
    #pragma unroll
    for (int off = 1; off < 256; off <<= 1) {
        unsigned u = (threadIdx.x >= off) ? sm[threadIdx.x - off] : 0u;
        __syncthreads();
        sm[threadIdx.x] += u;
        __syncthreads();
    }
    if (i < N_NODES) rowptr[i] = sm[threadIdx.x] - v;   // exclusive
    if (threadIdx.x == 255) bsum[blockIdx.x] = sm[255];
}

__global__ void scan_top_kernel(unsigned* __restrict__ bsum, unsigned* __restrict__ boff) {
    __shared__ unsigned sm[256];
    int i = threadIdx.x;
    unsigned v = (i < NB_SCAN) ? bsum[i] : 0u;
    sm[i] = v;
    __syncthreads();
    #pragma unroll
    for (int off = 1; off < 256; off <<= 1) {
        unsigned u = (i >= off) ? sm[i - off] : 0u;
        __syncthreads();
        sm[i] += u;
        __syncthreads();
    }
    if (i < NB_SCAN) boff[i] = sm[i] - v;   // exclusive
}

__global__ void scan_add_kernel(unsigned* __restrict__ rowptr, const unsigned* __restrict__ boff) {
    int i = blockIdx.x * 256 + threadIdx.x;
    if (i < N_NODES) rowptr[i] += boff[blockIdx.x];
    if (i == 0) rowptr[N_NODES] = ETOT;
}

__global__ void fill_kernel(const int* __restrict__ ei, const unsigned* __restrict__ rowptr,
                            unsigned* __restrict__ cursor, int* __restrict__ col) {
    int e = blockIdx.x * blockDim.x + threadIdx.x;
    if (e >= ETOT) return;
    int s, t; edge_sd(ei, e, s, t);
    unsigned pos = atomicAdd(&cursor[t], 1u);
    col[rowptr[t] + pos] = s;
}

// ============ W1 pre-pack into MFMA B-fragment layout (bf16) ============
// Wp index: ((k0*4 + cb)*64 + lane)*8 + j  <-  W[(k0*32 + (lane>>4)*8 + j)*64 + cb*16 + (lane&15)]
__global__ void packW_kernel(const float* __restrict__ W, short* __restrict__ Wp) {
    int idx = blockIdx.x * 256 + threadIdx.x;   // (k0*4+cb)*64+lane
    if (idx >= KB * 4 * 64) return;
    int lane = idx & 63;
    int cb = (idx >> 6) & 3;
    int k0 = idx >> 8;
    int colg = cb * 16 + (lane & 15);
    int kbase = k0 * 32 + (lane >> 4) * 8;
    short8v v;
    #pragma unroll
    for (int j = 0; j < 8; j++)
        v[j] = f2bf(W[(kbase + j) * HD + colg]);
    *reinterpret_cast<short8v*>(&Wp[(long)idx * 8]) = v;
}

// ============ layer 1 projection via MFMA: h = bf16(x) @ bf16(W1) ============
// one wave per 16-row tile; no LDS, no barriers; streams x at HBM speed
__global__ __launch_bounds__(256) void gemm1_mfma(const float* __restrict__ x,
                                                  const short* __restrict__ Wp,
                                                  float* __restrict__ h) {
    int wave = threadIdx.x >> 6;
    int lane = threadIdx.x & 63;
    int tile = blockIdx.x * 4 + wave;
    if (tile >= NTILE) return;
    int arow = tile * 16 + (lane & 15);
    const float* xp = x + (long)arow * F_IN + (lane >> 4) * 8;
    const short8v* wp = reinterpret_cast<const short8v*>(Wp) + lane;
    f32x4 acc0 = {}, acc1 = {}, acc2 = {}, acc3 = {};
    for (int k0 = 0; k0 < KB; k0++) {
        float4 a0 = *reinterpret_cast<const float4*>(xp);
        float4 a1 = *reinterpret_cast<const float4*>(xp + 4);
        xp += 32;
        short8v af;
        af[0] = f2bf(a0.x); af[1] = f2bf(a0.y); af[2] = f2bf(a0.z); af[3] = f2bf(a0.w);
        af[4] = f2bf(a1.x); af[5] = f2bf(a1.y); af[6] = f2bf(a1.z); af[7] = f2bf(a1.w);
        short8v b0 = wp[0 * 64];
        short8v b1 = wp[1 * 64];
        short8v b2 = wp[2 * 64];
        short8v b3 = wp[3 * 64];
        wp += 4 * 64;
        acc0 = __builtin_amdgcn_mfma_f32_16x16x32_bf16(af, b0, acc0, 0, 0, 0);
        acc1 = __builtin_amdgcn_mfma_f32_16x16x32_bf16(af, b1, acc1, 0, 0, 0);
        acc2 = __builtin_amdgcn_mfma_f32_16x16x32_bf16(af, b2, acc2, 0, 0, 0);
        acc3 = __builtin_amdgcn_mfma_f32_16x16x32_bf16(af, b3, acc3, 0, 0, 0);
    }
    // C/D layout: col = lane&15 (+16*cb), row = tile*16 + (lane>>4)*4 + r
    int c0 = lane & 15;
    long rbase = (long)(tile * 16 + (lane >> 4) * 4) * HD;
    #pragma unroll
    for (int r = 0; r < 4; r++) {
        h[rbase + r * HD + c0]      = acc0[r];
        h[rbase + r * HD + 16 + c0] = acc1[r];
        h[rbase + r * HD + 32 + c0] = acc2[r];
        h[rbase + r * HD + 48 + c0] = acc3[r];
    }
}

// ---------- per-node attention terms (layer 1) ----------
__global__ void att1_kernel(const float* __restrict__ h,
                            const float* __restrict__ asrc_w, const float* __restrict__ adst_w,
                            float* __restrict__ a_src, float* __restrict__ a_dst) {
    int idx = blockIdx.x * blockDim.x + threadIdx.x;   // n*8 + head
    if (idx >= N_NODES * H1) return;
    int n = idx >> 3, hh = idx & 7;
    float s = 0.f, dd = 0.f;
    #pragma unroll
    for (int d = 0; d < 8; d++) {
        float v = h[(long)n * 64 + hh * 8 + d];
        s  += v * asrc_w[hh * 8 + d];
        dd += v * adst_w[hh * 8 + d];
    }
    a_src[idx] = s;
    a_dst[idx] = dd;
}

// ---------- layer-1 fused segment softmax + aggregation (wave per node) ----------
__global__ __launch_bounds__(256) void agg1_kernel(const unsigned* __restrict__ rowptr,
                                                   const int* __restrict__ col,
                                                   const float* __restrict__ a_src,
                                                   const float* __restrict__ a_dst,
                                                   const float* __restrict__ h,
                                                   float* __restrict__ out) {
    int n = blockIdx.x * 4 + (threadIdx.x >> 6);
    if (n >= N_NODES) return;
    int k = threadIdx.x & 63;
    int hh = k >> 3;
    float ad = a_dst[n * 8 + hh];
    int r0 = rowptr[n], r1 = rowptr[n + 1];
    float acc = 0.f, z = 0.f;
    for (int e = r0; e < r1; ++e) {
        int s = col[e];
        float p = __expf(lrelu(a_src[s * 8 + hh] + ad));
        z += p;
        acc += p * h[(long)s * 64 + k];
    }
    out[(long)n * 64 + k] = acc / (z + 1e-16f);
}

// ---------- layer-2 projection (+b1 fused) + attention terms ----------
__global__ __launch_bounds__(256) void proj2_kernel(const float* __restrict__ out1,
                                                    const float* __restrict__ b1,
                                                    const float* __restrict__ W2,
                                                    const float* __restrict__ asrc2_w,
                                                    const float* __restrict__ adst2_w,
                                                    float* __restrict__ h2p,
                                                    float* __restrict__ a_src2,
                                                    float* __restrict__ a_dst2) {
    int gtid = blockIdx.x * blockDim.x + threadIdx.x;
    int n = gtid >> 6;
    int lane = threadIdx.x & 63;
    if (n >= N_NODES) return;
    float v = out1[(long)n * 64 + lane] + b1[lane];
    float part[NC];
    #pragma unroll
    for (int c = 0; c < NC; c++) part[c] = v * W2[lane * NC + c];
    #pragma unroll
    for (int off = 32; off >= 1; off >>= 1)
        #pragma unroll
        for (int c = 0; c < NC; c++) part[c] += __shfl_xor(part[c], off, 64);
    if (lane == 0) {
        float as = 0.f, ad = 0.f;
        #pragma unroll
        for (int c = 0; c < NC; c++) {
            h2p[n * NC + c] = part[c];
            as += part[c] * asrc2_w[c];
            ad += part[c] * adst2_w[c];
        }
        a_src2[n] = as;
        a_dst2[n] = ad;
    }
}

// ---------- layer-2 fused softmax+agg+bias+log_softmax (thread per node) ----------
__global__ void agg2_kernel(const unsigned* __restrict__ rowptr, const int* __restrict__ col,
                            const float* __restrict__ a_src2, const float* __restrict__ a_dst2,
                            const float* __restrict__ h2p, const float* __restrict__ b2,
                            float* __restrict__ y) {
    int n = blockIdx.x * blockDim.x + threadIdx.x;
    if (n >= N_NODES) return;
    float ad = a_dst2[n];
    int r0 = rowptr[n], r1 = rowptr[n + 1];
    float acc[NC] = {};
    float z = 0.f;
    for (int e = r0; e < r1; ++e) {
        int s = col[e];
        float p = __expf(lrelu(a_src2[s] + ad));
        z += p;
        #pragma unroll
        for (int c = 0; c < NC; c++) acc[c] += p * h2p[s * NC + c];
    }
    float inv = 1.f / (z + 1e-16f);
    float l[NC], mx = -3.4e38f;
    #pragma unroll
    for (int c = 0; c < NC; c++) {
        l[c] = acc[c] * inv + b2[c];
        mx = fmaxf(mx, l[c]);
    }
    float ssum = 0.f;
    #pragma unroll
    for (int c = 0; c < NC; c++) ssum += __expf(l[c] - mx);
    float lse = __logf(ssum);
    #pragma unroll
    for (int c = 0; c < NC; c++) y[n * NC + c] = l[c] - mx - lse;
}

extern "C" void kernel_launch(void* const* d_in, const int* in_sizes, int n_in,
                              void* d_out, int out_size, void* d_ws, size_t ws_size,
                              hipStream_t stream) {
    const float* x        = (const float*)d_in[0];
    const int*   ei       = (const int*)d_in[1];
    const float* W1       = (const float*)d_in[2];
    const float* att_src1 = (const float*)d_in[3];
    const float* att_dst1 = (const float*)d_in[4];
    const float* b1       = (const float*)d_in[5];
    const float* W2       = (const float*)d_in[6];
    const float* att_src2 = (const float*)d_in[7];
    const float* att_dst2 = (const float*)d_in[8];
    const float* b2       = (const float*)d_in[9];
    float* y = (float*)d_out;

    // workspace layout
    float* ws      = (float*)d_ws;
    float* h1p     = ws;                                  // N*64
    float* a_src1  = h1p + (long)N_NODES * 64;            // N*8
    float* a_dst1  = a_src1 + N_NODES * 8;                // N*8
    float* out1    = a_dst1 + N_NODES * 8;                // N*64
    float* h2p     = out1 + (long)N_NODES * 64;           // N*5
    float* a_src2  = h2p + N_NODES * NC;                  // N
    float* a_dst2  = a_src2 + N_NODES;                    // N
    unsigned* deg    = (unsigned*)(a_dst2 + N_NODES);     // N
    unsigned* cursor = deg + N_NODES;                     // N
    unsigned* rowptr = cursor + N_NODES;                  // N+1
    unsigned* bsum   = rowptr + N_NODES + 1;              // 256
    unsigned* boff   = bsum + 256;                        // 256
    int*      col    = (int*)(boff + 256);                // ETOT
    short*    Wp     = (short*)(col + ETOT);              // 72*4*64*8 = 147456 shorts

    // ---- CSR build + W pre-pack (per call, graph-safe) ----
    hipMemsetAsync(deg,    0, N_NODES * sizeof(unsigned), stream);
    hipMemsetAsync(cursor, 0, N_NODES * sizeof(unsigned), stream);
    hist_kernel<<<(ETOT + 255) / 256, 256, 0, stream>>>(ei, deg);
    packW_kernel<<<(KB * 4 * 64 + 255) / 256, 256, 0, stream>>>(W1, Wp);
    scan_block_kernel<<<NB_SCAN, 256, 0, stream>>>(deg, rowptr, bsum);
    scan_top_kernel<<<1, 256, 0, stream>>>(bsum, boff);
    scan_add_kernel<<<NB_SCAN, 256, 0, stream>>>(rowptr, boff);
    fill_kernel<<<(ETOT + 255) / 256, 256, 0, stream>>>(ei, rowptr, cursor, col);

    // ---- layer 1 ----
    gemm1_mfma<<<(NTILE + 3) / 4, 256, 0, stream>>>(x, Wp, h1p);
    att1_kernel<<<(N_NODES * 8 + 255) / 256, 256, 0, stream>>>(h1p, att_src1, att_dst1, a_src1, a_dst1);
    agg1_kernel<<<(N_NODES + 3) / 4, 256, 0, stream>>>(rowptr, col, a_src1, a_dst1, h1p, out1);

    // ---- layer 2 ----
    proj2_kernel<<<(N_NODES * 64 + 255) / 256, 256, 0, stream>>>(out1, b1, W2, att_src2, att_dst2, h2p, a_src2, a_dst2);
    agg2_kernel<<<(N_NODES + 255) / 256, 256, 0, stream>>>(rowptr, col, a_src2, a_dst2, h2p, b2, y);
}

// Round 5
// 507.361 us; speedup vs baseline: 3.0459x; 1.0629x over previous
//
#include <hip/hip_runtime.h>

#define N_NODES 50000
#define N_EDGES 1600000
#define ETOT (N_EDGES + N_NODES)   // 1,650,000 (self-loops appended)
#define F_IN 2304
#define HD 64    // H1*D1
#define H1 8
#define D1 8
#define NC 5
#define NB_SCAN ((N_NODES + 255) / 256)   // 196
#define KB (F_IN / 32)                    // 72 K-blocks
#define NTILE (N_NODES / 16)              // 3125 wave tiles

typedef __attribute__((ext_vector_type(8))) short short8v;
typedef __attribute__((ext_vector_type(4))) float f32x4;

__device__ __forceinline__ float lrelu(float x) { return x > 0.f ? x : 0.2f * x; }

__device__ __forceinline__ unsigned short f2bf(float f) {   // RNE fp32->bf16
    unsigned u = __float_as_uint(f);
    u += 0x7fffu + ((u >> 16) & 1u);
    return (unsigned short)(u >> 16);
}
__device__ __forceinline__ float bf2f(unsigned short u) {
    return __uint_as_float(((unsigned)u) << 16);
}

__device__ __forceinline__ void edge_sd(const int* __restrict__ ei, int e, int& s, int& t) {
    if (e < N_EDGES) { s = ei[e]; t = ei[N_EDGES + e]; }
    else { s = e - N_EDGES; t = s; }
}

// ================= CSR build =================
__global__ void hist_kernel(const int* __restrict__ ei, unsigned* __restrict__ deg) {
    int e = blockIdx.x * blockDim.x + threadIdx.x;
    if (e >= ETOT) return;
    int s, t; edge_sd(ei, e, s, t);
    atomicAdd(&deg[t], 1u);
}

__global__ void scan_block_kernel(const unsigned* __restrict__ deg,
                                  unsigned* __restrict__ rowptr,
                                  unsigned* __restrict__ bsum) {
    __shared__ unsigned sm[256];
    int i = blockIdx.x * 256 + threadIdx.x;
    unsigned v = (i < N_NODES) ? deg[i] : 0u;
    sm[threadIdx.x] = v;
    __syncthreads();
    #pragma unroll
    for (int off = 1; off < 256; off <<= 1) {
        unsigned u = (threadIdx.x >= off) ? sm[threadIdx.x - off] : 0u;
        __syncthreads();
        sm[threadIdx.x] += u;
        __syncthreads();
    }
    if (i < N_NODES) rowptr[i] = sm[threadIdx.x] - v;   // exclusive
    if (threadIdx.x == 255) bsum[blockIdx.x] = sm[255];
}

__global__ void scan_top_kernel(unsigned* __restrict__ bsum, unsigned* __restrict__ boff) {
    __shared__ unsigned sm[256];
    int i = threadIdx.x;
    unsigned v = (i < NB_SCAN) ? bsum[i] : 0u;
    sm[i] = v;
    __syncthreads();
    #pragma unroll
    for (int off = 1; off < 256; off <<= 1) {
        unsigned u = (i >= off) ? sm[i - off] : 0u;
        __syncthreads();
        sm[i] += u;
        __syncthreads();
    }
    if (i < NB_SCAN) boff[i] = sm[i] - v;   // exclusive
}

__global__ void scan_add_kernel(unsigned* __restrict__ rowptr, const unsigned* __restrict__ boff) {
    int i = blockIdx.x * 256 + threadIdx.x;
    if (i < N_NODES) rowptr[i] += boff[blockIdx.x];
    if (i == 0) rowptr[N_NODES] = ETOT;
}

__global__ void fill_kernel(const int* __restrict__ ei, const unsigned* __restrict__ rowptr,
                            unsigned* __restrict__ cursor, int* __restrict__ col) {
    int e = blockIdx.x * blockDim.x + threadIdx.x;
    if (e >= ETOT) return;
    int s, t; edge_sd(ei, e, s, t);
    unsigned pos = atomicAdd(&cursor[t], 1u);
    col[rowptr[t] + pos] = s;
}

// ============ W1 pre-pack into MFMA B-fragment layout (bf16) ============
__global__ void packW_kernel(const float* __restrict__ W, short* __restrict__ Wp) {
    int idx = blockIdx.x * 256 + threadIdx.x;   // (k0*4+cb)*64+lane
    if (idx >= KB * 4 * 64) return;
    int lane = idx & 63;
    int cb = (idx >> 6) & 3;
    int k0 = idx >> 8;
    int colg = cb * 16 + (lane & 15);
    int kbase = k0 * 32 + (lane >> 4) * 8;
    short8v v;
    #pragma unroll
    for (int j = 0; j < 8; j++)
        v[j] = (short)f2bf(W[(kbase + j) * HD + colg]);
    *reinterpret_cast<short8v*>(&Wp[(long)idx * 8]) = v;
}

// ============ layer 1 projection via MFMA: hb = bf16(bf16(x) @ bf16(W1)) ============
// one wave per 16-row tile; no LDS, no barriers; streams x nontemporally
__global__ __launch_bounds__(256) void gemm1_mfma(const float* __restrict__ x,
                                                  const short* __restrict__ Wp,
                                                  unsigned short* __restrict__ hb) {
    int wave = threadIdx.x >> 6;
    int lane = threadIdx.x & 63;
    int tile = blockIdx.x * 4 + wave;
    if (tile >= NTILE) return;
    int arow = tile * 16 + (lane & 15);
    const f32x4* xp = reinterpret_cast<const f32x4*>(x + (long)arow * F_IN + (lane >> 4) * 8);
    const short8v* wp = reinterpret_cast<const short8v*>(Wp) + lane;
    f32x4 acc0 = {}, acc1 = {}, acc2 = {}, acc3 = {};
    f32x4 a0 = __builtin_nontemporal_load(xp);
    f32x4 a1 = __builtin_nontemporal_load(xp + 1);
    xp += 8;
    for (int k0 = 0; k0 < KB - 1; k0++) {
        short8v b0 = wp[0 * 64];
        short8v b1 = wp[1 * 64];
        short8v b2 = wp[2 * 64];
        short8v b3 = wp[3 * 64];
        wp += 4 * 64;
        f32x4 n0 = __builtin_nontemporal_load(xp);
        f32x4 n1 = __builtin_nontemporal_load(xp + 1);
        xp += 8;
        short8v af;
        #pragma unroll
        for (int j = 0; j < 4; j++) af[j] = (short)f2bf(a0[j]);
        #pragma unroll
        for (int j = 0; j < 4; j++) af[4 + j] = (short)f2bf(a1[j]);
        acc0 = __builtin_amdgcn_mfma_f32_16x16x32_bf16(af, b0, acc0, 0, 0, 0);
        acc1 = __builtin_amdgcn_mfma_f32_16x16x32_bf16(af, b1, acc1, 0, 0, 0);
        acc2 = __builtin_amdgcn_mfma_f32_16x16x32_bf16(af, b2, acc2, 0, 0, 0);
        acc3 = __builtin_amdgcn_mfma_f32_16x16x32_bf16(af, b3, acc3, 0, 0, 0);
        a0 = n0; a1 = n1;
    }
    {   // last K-block
        short8v b0 = wp[0 * 64];
        short8v b1 = wp[1 * 64];
        short8v b2 = wp[2 * 64];
        short8v b3 = wp[3 * 64];
        short8v af;
        #pragma unroll
        for (int j = 0; j < 4; j++) af[j] = (short)f2bf(a0[j]);
        #pragma unroll
        for (int j = 0; j < 4; j++) af[4 + j] = (short)f2bf(a1[j]);
        acc0 = __builtin_amdgcn_mfma_f32_16x16x32_bf16(af, b0, acc0, 0, 0, 0);
        acc1 = __builtin_amdgcn_mfma_f32_16x16x32_bf16(af, b1, acc1, 0, 0, 0);
        acc2 = __builtin_amdgcn_mfma_f32_16x16x32_bf16(af, b2, acc2, 0, 0, 0);
        acc3 = __builtin_amdgcn_mfma_f32_16x16x32_bf16(af, b3, acc3, 0, 0, 0);
    }
    // C/D layout: col = lane&15 (+16*cb), row = tile*16 + (lane>>4)*4 + r
    int c0 = lane & 15;
    long rbase = (long)(tile * 16 + (lane >> 4) * 4) * HD;
    #pragma unroll
    for (int r = 0; r < 4; r++) {
        hb[rbase + r * HD + c0]      = f2bf(acc0[r]);
        hb[rbase + r * HD + 16 + c0] = f2bf(acc1[r]);
        hb[rbase + r * HD + 32 + c0] = f2bf(acc2[r]);
        hb[rbase + r * HD + 48 + c0] = f2bf(acc3[r]);
    }
}

// ---------- per-node attention terms (layer 1), bf16 h ----------
__global__ void att1_kernel(const unsigned short* __restrict__ hb,
                            const float* __restrict__ asrc_w, const float* __restrict__ adst_w,
                            float* __restrict__ a_src, float* __restrict__ a_dst) {
    int idx = blockIdx.x * blockDim.x + threadIdx.x;   // n*8 + head
    if (idx >= N_NODES * H1) return;
    int n = idx >> 3, hh = idx & 7;
    short8v v = *reinterpret_cast<const short8v*>(&hb[(long)n * 64 + hh * 8]);
    float s = 0.f, dd = 0.f;
    #pragma unroll
    for (int d = 0; d < 8; d++) {
        float f = bf2f((unsigned short)v[d]);
        s  += f * asrc_w[hh * 8 + d];
        dd += f * adst_w[hh * 8 + d];
    }
    a_src[idx] = s;
    a_dst[idx] = dd;
}

// ---------- layer-1 fused segment softmax + aggregation (wave per node) ----------
__global__ __launch_bounds__(256) void agg1_kernel(const unsigned* __restrict__ rowptr,
                                                   const int* __restrict__ col,
                                                   const float* __restrict__ a_src,
                                                   const float* __restrict__ a_dst,
                                                   const unsigned short* __restrict__ hb,
                                                   float* __restrict__ out) {
    int n = blockIdx.x * 4 + (threadIdx.x >> 6);
    if (n >= N_NODES) return;
    int k = threadIdx.x & 63;
    int hh = k >> 3;
    float ad = a_dst[n * 8 + hh];
    int r0 = rowptr[n], r1 = rowptr[n + 1];
    float acc = 0.f, z = 0.f;
    int e = r0;
    for (; e + 1 < r1; e += 2) {   // 2-way unroll: two gathers in flight
        int s0 = col[e], s1 = col[e + 1];
        float as0 = a_src[s0 * 8 + hh];
        float as1 = a_src[s1 * 8 + hh];
        unsigned short u0 = hb[(long)s0 * 64 + k];
        unsigned short u1 = hb[(long)s1 * 64 + k];
        float p0 = __expf(lrelu(as0 + ad));
        float p1 = __expf(lrelu(as1 + ad));
        z += p0 + p1;
        acc += p0 * bf2f(u0) + p1 * bf2f(u1);
    }
    if (e < r1) {
        int s0 = col[e];
        float p0 = __expf(lrelu(a_src[s0 * 8 + hh] + ad));
        z += p0;
        acc += p0 * bf2f(hb[(long)s0 * 64 + k]);
    }
    out[(long)n * 64 + k] = acc / (z + 1e-16f);
}

// ---------- layer-2 projection (+b1 fused) + attention terms ----------
__global__ __launch_bounds__(256) void proj2_kernel(const float* __restrict__ out1,
                                                    const float* __restrict__ b1,
                                                    const float* __restrict__ W2,
                                                    const float* __restrict__ asrc2_w,
                                                    const float* __restrict__ adst2_w,
                                                    float* __restrict__ h2p,
                                                    float* __restrict__ a_src2,
                                                    float* __restrict__ a_dst2) {
    int gtid = blockIdx.x * blockDim.x + threadIdx.x;
    int n = gtid >> 6;
    int lane = threadIdx.x & 63;
    if (n >= N_NODES) return;
    float v = out1[(long)n * 64 + lane] + b1[lane];
    float part[NC];
    #pragma unroll
    for (int c = 0; c < NC; c++) part[c] = v * W2[lane * NC + c];
    #pragma unroll
    for (int off = 32; off >= 1; off >>= 1)
        #pragma unroll
        for (int c = 0; c < NC; c++) part[c] += __shfl_xor(part[c], off, 64);
    if (lane == 0) {
        float as = 0.f, ad = 0.f;
        #pragma unroll
        for (int c = 0; c < NC; c++) {
            h2p[n * NC + c] = part[c];
            as += part[c] * asrc2_w[c];
            ad += part[c] * adst2_w[c];
        }
        a_src2[n] = as;
        a_dst2[n] = ad;
    }
}

// ---------- layer-2 fused softmax+agg+bias+log_softmax (thread per node) ----------
__global__ void agg2_kernel(const unsigned* __restrict__ rowptr, const int* __restrict__ col,
                            const float* __restrict__ a_src2, const float* __restrict__ a_dst2,
                            const float* __restrict__ h2p, const float* __restrict__ b2,
                            float* __restrict__ y) {
    int n = blockIdx.x * blockDim.x + threadIdx.x;
    if (n >= N_NODES) return;
    float ad = a_dst2[n];
    int r0 = rowptr[n], r1 = rowptr[n + 1];
    float acc[NC] = {};
    float z = 0.f;
    for (int e = r0; e < r1; ++e) {
        int s = col[e];
        float p = __expf(lrelu(a_src2[s] + ad));
        z += p;
        #pragma unroll
        for (int c = 0; c < NC; c++) acc[c] += p * h2p[s * NC + c];
    }
    float inv = 1.f / (z + 1e-16f);
    float l[NC], mx = -3.4e38f;
    #pragma unroll
    for (int c = 0; c < NC; c++) {
        l[c] = acc[c] * inv + b2[c];
        mx = fmaxf(mx, l[c]);
    }
    float ssum = 0.f;
    #pragma unroll
    for (int c = 0; c < NC; c++) ssum += __expf(l[c] - mx);
    float lse = __logf(ssum);
    #pragma unroll
    for (int c = 0; c < NC; c++) y[n * NC + c] = l[c] - mx - lse;
}

extern "C" void kernel_launch(void* const* d_in, const int* in_sizes, int n_in,
                              void* d_out, int out_size, void* d_ws, size_t ws_size,
                              hipStream_t stream) {
    const float* x        = (const float*)d_in[0];
    const int*   ei       = (const int*)d_in[1];
    const float* W1       = (const float*)d_in[2];
    const float* att_src1 = (const float*)d_in[3];
    const float* att_dst1 = (const float*)d_in[4];
    const float* b1       = (const float*)d_in[5];
    const float* W2       = (const float*)d_in[6];
    const float* att_src2 = (const float*)d_in[7];
    const float* att_dst2 = (const float*)d_in[8];
    const float* b2       = (const float*)d_in[9];
    float* y = (float*)d_out;

    // workspace layout
    unsigned short* hb = (unsigned short*)d_ws;           // N*64 bf16
    float* a_src1  = (float*)(hb + (long)N_NODES * 64);   // N*8
    float* a_dst1  = a_src1 + N_NODES * 8;                // N*8
    float* out1    = a_dst1 + N_NODES * 8;                // N*64
    float* h2p     = out1 + (long)N_NODES * 64;           // N*5
    float* a_src2  = h2p + N_NODES * NC;                  // N
    float* a_dst2  = a_src2 + N_NODES;                    // N
    unsigned* deg    = (unsigned*)(a_dst2 + N_NODES);     // N
    unsigned* cursor = deg + N_NODES;                     // N
    unsigned* rowptr = cursor + N_NODES;                  // N+1
    unsigned* bsum   = rowptr + N_NODES + 1;              // 256
    unsigned* boff   = bsum + 256;                        // 256
    int*      col    = (int*)(boff + 256);                // ETOT
    short*    Wp     = (short*)(col + ETOT);              // 147456 shorts

    // ---- CSR build + W pre-pack (per call, graph-safe) ----
    hipMemsetAsync(deg,    0, N_NODES * sizeof(unsigned), stream);
    hipMemsetAsync(cursor, 0, N_NODES * sizeof(unsigned), stream);
    hist_kernel<<<(ETOT + 255) / 256, 256, 0, stream>>>(ei, deg);
    packW_kernel<<<(KB * 4 * 64 + 255) / 256, 256, 0, stream>>>(W1, Wp);
    scan_block_kernel<<<NB_SCAN, 256, 0, stream>>>(deg, rowptr, bsum);
    scan_top_kernel<<<1, 256, 0, stream>>>(bsum, boff);
    scan_add_kernel<<<NB_SCAN, 256, 0, stream>>>(rowptr, boff);
    fill_kernel<<<(ETOT + 255) / 256, 256, 0, stream>>>(ei, rowptr, cursor, col);

    // ---- layer 1 ----
    gemm1_mfma<<<(NTILE + 3) / 4, 256, 0, stream>>>(x, Wp, hb);
    att1_kernel<<<(N_NODES * 8 + 255) / 256, 256, 0, stream>>>(hb, att_src1, att_dst1, a_src1, a_dst1);
    agg1_kernel<<<(N_NODES + 3) / 4, 256, 0, stream>>>(rowptr, col, a_src1, a_dst1, hb, out1);

    // ---- layer 2 ----
    proj2_kernel<<<(N_NODES * 64 + 255) / 256, 256, 0, stream>>>(out1, b1, W2, att_src2, att_dst2, h2p, a_src2, a_dst2);
    agg2_kernel<<<(N_NODES + 255) / 256, 256, 0, stream>>>(rowptr, col, a_src2, a_dst2, h2p, b2, y);
}

// Round 6
// 450.951 us; speedup vs baseline: 3.4269x; 1.1251x over previous
//
#include <hip/hip_runtime.h>

#define N_NODES 50000
#define N_EDGES 1600000
#define ETOT (N_EDGES + N_NODES)   // 1,650,000 (self-loops appended)
#define F_IN 2304
#define HD 64    // H1*D1
#define H1 8
#define D1 8
#define NC 5
#define NB_SCAN ((N_NODES + 255) / 256)   // 196
#define KB (F_IN / 32)                    // 72 K-blocks
#define NTILE (N_NODES / 16)              // 3125 wave tiles

typedef __attribute__((ext_vector_type(8))) short short8v;
typedef __attribute__((ext_vector_type(4))) float f32x4;

__device__ __forceinline__ float lrelu(float x) { return x > 0.f ? x : 0.2f * x; }

__device__ __forceinline__ unsigned short f2bf(float f) {   // RNE fp32->bf16
    unsigned u = __float_as_uint(f);
    u += 0x7fffu + ((u >> 16) & 1u);
    return (unsigned short)(u >> 16);
}
__device__ __forceinline__ float bf2f(unsigned short u) {
    return __uint_as_float(((unsigned)u) << 16);
}

__device__ __forceinline__ void edge_sd(const int* __restrict__ ei, int e, int& s, int& t) {
    if (e < N_EDGES) { s = ei[e]; t = ei[N_EDGES + e]; }
    else { s = e - N_EDGES; t = s; }
}

// ================= CSR build =================
__global__ void hist_kernel(const int* __restrict__ ei, unsigned* __restrict__ deg) {
    int e = blockIdx.x * blockDim.x + threadIdx.x;
    if (e >= ETOT) return;
    int s, t; edge_sd(ei, e, s, t);
    atomicAdd(&deg[t], 1u);
}

__global__ void scan_block_kernel(const unsigned* __restrict__ deg,
                                  unsigned* __restrict__ rowptr,
                                  unsigned* __restrict__ bsum) {
    __shared__ unsigned sm[256];
    int i = blockIdx.x * 256 + threadIdx.x;
    unsigned v = (i < N_NODES) ? deg[i] : 0u;
    sm[threadIdx.x] = v;
    __syncthreads();
    #pragma unroll
    for (int off = 1; off < 256; off <<= 1) {
        unsigned u = (threadIdx.x >= off) ? sm[threadIdx.x - off] : 0u;
        __syncthreads();
        sm[threadIdx.x] += u;
        __syncthreads();
    }
    if (i < N_NODES) rowptr[i] = sm[threadIdx.x] - v;   // exclusive
    if (threadIdx.x == 255) bsum[blockIdx.x] = sm[255];
}

__global__ void scan_top_kernel(unsigned* __restrict__ bsum, unsigned* __restrict__ boff) {
    __shared__ unsigned sm[256];
    int i = threadIdx.x;
    unsigned v = (i < NB_SCAN) ? bsum[i] : 0u;
    sm[i] = v;
    __syncthreads();
    #pragma unroll
    for (int off = 1; off < 256; off <<= 1) {
        unsigned u = (i >= off) ? sm[i - off] : 0u;
        __syncthreads();
        sm[i] += u;
        __syncthreads();
    }
    if (i < NB_SCAN) boff[i] = sm[i] - v;   // exclusive
}

__global__ void scan_add_kernel(unsigned* __restrict__ rowptr, const unsigned* __restrict__ boff) {
    int i = blockIdx.x * 256 + threadIdx.x;
    if (i < N_NODES) rowptr[i] += boff[blockIdx.x];
    if (i == 0) rowptr[N_NODES] = ETOT;
}

__global__ void fill_kernel(const int* __restrict__ ei, const unsigned* __restrict__ rowptr,
                            unsigned* __restrict__ cursor, int* __restrict__ col) {
    int e = blockIdx.x * blockDim.x + threadIdx.x;
    if (e >= ETOT) return;
    int s, t; edge_sd(ei, e, s, t);
    unsigned pos = atomicAdd(&cursor[t], 1u);
    col[rowptr[t] + pos] = s;
}

// ============ W1 pre-pack into MFMA B-fragment layout (bf16) ============
__global__ void packW_kernel(const float* __restrict__ W, short* __restrict__ Wp) {
    int idx = blockIdx.x * 256 + threadIdx.x;   // (k0*4+cb)*64+lane
    if (idx >= KB * 4 * 64) return;
    int lane = idx & 63;
    int cb = (idx >> 6) & 3;
    int k0 = idx >> 8;
    int colg = cb * 16 + (lane & 15);
    int kbase = k0 * 32 + (lane >> 4) * 8;
    short8v v;
    #pragma unroll
    for (int j = 0; j < 8; j++)
        v[j] = (short)f2bf(W[(kbase + j) * HD + colg]);
    *reinterpret_cast<short8v*>(&Wp[(long)idx * 8]) = v;
}

// ============ layer 1 projection via MFMA + fused attention terms ============
// one wave per 16-row tile; no LDS, no barriers; streams x nontemporally;
// 2-deep prefetch; epilogue computes a_src/a_dst via 8-lane shfl reduce
__global__ __launch_bounds__(256) void gemm1_mfma(const float* __restrict__ x,
                                                  const short* __restrict__ Wp,
                                                  const float* __restrict__ asrc_w,
                                                  const float* __restrict__ adst_w,
                                                  unsigned short* __restrict__ hb,
                                                  float* __restrict__ a_src,
                                                  float* __restrict__ a_dst) {
    int wave = threadIdx.x >> 6;
    int lane = threadIdx.x & 63;
    int tile = blockIdx.x * 4 + wave;
    if (tile >= NTILE) return;
    int arow = tile * 16 + (lane & 15);
    const f32x4* xp = reinterpret_cast<const f32x4*>(x + (long)arow * F_IN + (lane >> 4) * 8);
    const short8v* wp = reinterpret_cast<const short8v*>(Wp) + lane;
    f32x4 acc0 = {}, acc1 = {}, acc2 = {}, acc3 = {};
    f32x4 x0 = __builtin_nontemporal_load(xp);
    f32x4 x1 = __builtin_nontemporal_load(xp + 1);
    f32x4 y0 = __builtin_nontemporal_load(xp + 8);
    f32x4 y1 = __builtin_nontemporal_load(xp + 9);
    xp += 16;
    for (int k0 = 0; k0 < KB - 2; k0++) {
        short8v b0 = wp[0 * 64];
        short8v b1 = wp[1 * 64];
        short8v b2 = wp[2 * 64];
        short8v b3 = wp[3 * 64];
        wp += 4 * 64;
        f32x4 z0 = __builtin_nontemporal_load(xp);
        f32x4 z1 = __builtin_nontemporal_load(xp + 1);
        xp += 8;
        short8v af;
        #pragma unroll
        for (int j = 0; j < 4; j++) af[j] = (short)f2bf(x0[j]);
        #pragma unroll
        for (int j = 0; j < 4; j++) af[4 + j] = (short)f2bf(x1[j]);
        acc0 = __builtin_amdgcn_mfma_f32_16x16x32_bf16(af, b0, acc0, 0, 0, 0);
        acc1 = __builtin_amdgcn_mfma_f32_16x16x32_bf16(af, b1, acc1, 0, 0, 0);
        acc2 = __builtin_amdgcn_mfma_f32_16x16x32_bf16(af, b2, acc2, 0, 0, 0);
        acc3 = __builtin_amdgcn_mfma_f32_16x16x32_bf16(af, b3, acc3, 0, 0, 0);
        x0 = y0; x1 = y1; y0 = z0; y1 = z1;
    }
    #pragma unroll
    for (int tb = 0; tb < 2; tb++) {   // last two K-blocks (x pair, then y pair)
        short8v b0 = wp[0 * 64];
        short8v b1 = wp[1 * 64];
        short8v b2 = wp[2 * 64];
        short8v b3 = wp[3 * 64];
        wp += 4 * 64;
        short8v af;
        #pragma unroll
        for (int j = 0; j < 4; j++) af[j] = (short)f2bf(tb == 0 ? x0[j] : y0[j]);
        #pragma unroll
        for (int j = 0; j < 4; j++) af[4 + j] = (short)f2bf(tb == 0 ? x1[j] : y1[j]);
        acc0 = __builtin_amdgcn_mfma_f32_16x16x32_bf16(af, b0, acc0, 0, 0, 0);
        acc1 = __builtin_amdgcn_mfma_f32_16x16x32_bf16(af, b1, acc1, 0, 0, 0);
        acc2 = __builtin_amdgcn_mfma_f32_16x16x32_bf16(af, b2, acc2, 0, 0, 0);
        acc3 = __builtin_amdgcn_mfma_f32_16x16x32_bf16(af, b3, acc3, 0, 0, 0);
    }
    // C/D layout: col = cb*16 + (lane&15), row = tile*16 + (lane>>4)*4 + r
    int c0 = lane & 15;
    long rbase = (long)(tile * 16 + (lane >> 4) * 4) * HD;
    #pragma unroll
    for (int r = 0; r < 4; r++) {
        hb[rbase + r * HD + c0]      = f2bf(acc0[r]);
        hb[rbase + r * HD + 16 + c0] = f2bf(acc1[r]);
        hb[rbase + r * HD + 32 + c0] = f2bf(acc2[r]);
        hb[rbase + r * HD + 48 + c0] = f2bf(acc3[r]);
    }
    // fused attention terms: a_src[n,hh] = sum_d h[n][hh*8+d]*asrc_w[hh*8+d]
    // lane c0 holds cols {c0, c0+16, c0+32, c0+48}; head hh = col>>3 = 2*cb + (c0>>3)
    float wsv[4], wdv[4];
    #pragma unroll
    for (int cb = 0; cb < 4; cb++) {
        wsv[cb] = asrc_w[cb * 16 + c0];
        wdv[cb] = adst_w[cb * 16 + c0];
    }
    int nbase = tile * 16 + (lane >> 4) * 4;
    #pragma unroll
    for (int r = 0; r < 4; r++) {
        float a[4] = {acc0[r], acc1[r], acc2[r], acc3[r]};
        #pragma unroll
        for (int cb = 0; cb < 4; cb++) {
            float vs = a[cb] * wsv[cb];
            float vd = a[cb] * wdv[cb];
            vs += __shfl_xor(vs, 1, 64); vd += __shfl_xor(vd, 1, 64);
            vs += __shfl_xor(vs, 2, 64); vd += __shfl_xor(vd, 2, 64);
            vs += __shfl_xor(vs, 4, 64); vd += __shfl_xor(vd, 4, 64);
            if ((c0 & 7) == 0) {
                int hh = 2 * cb + (c0 >> 3);
                a_src[(nbase + r) * 8 + hh] = vs;
                a_dst[(nbase + r) * 8 + hh] = vd;
            }
        }
    }
}

// ---------- layer-1 fused segment softmax + aggregation (wave per node) ----------
__global__ __launch_bounds__(256) void agg1_kernel(const unsigned* __restrict__ rowptr,
                                                   const int* __restrict__ col,
                                                   const float* __restrict__ a_src,
                                                   const float* __restrict__ a_dst,
                                                   const unsigned short* __restrict__ hb,
                                                   float* __restrict__ out) {
    int n = blockIdx.x * 4 + (threadIdx.x >> 6);
    if (n >= N_NODES) return;
    int k = threadIdx.x & 63;
    int hh = k >> 3;
    float ad = a_dst[n * 8 + hh];
    int r0 = rowptr[n], r1 = rowptr[n + 1];
    float acc = 0.f, z = 0.f;
    int e = r0;
    for (; e + 3 < r1; e += 4) {   // 4-way unroll: four gathers in flight
        int s0 = col[e], s1 = col[e + 1], s2 = col[e + 2], s3 = col[e + 3];
        float as0 = a_src[s0 * 8 + hh];
        float as1 = a_src[s1 * 8 + hh];
        float as2 = a_src[s2 * 8 + hh];
        float as3 = a_src[s3 * 8 + hh];
        unsigned short u0 = hb[(long)s0 * 64 + k];
        unsigned short u1 = hb[(long)s1 * 64 + k];
        unsigned short u2 = hb[(long)s2 * 64 + k];
        unsigned short u3 = hb[(long)s3 * 64 + k];
        float p0 = __expf(lrelu(as0 + ad));
        float p1 = __expf(lrelu(as1 + ad));
        float p2 = __expf(lrelu(as2 + ad));
        float p3 = __expf(lrelu(as3 + ad));
        z += (p0 + p1) + (p2 + p3);
        acc += p0 * bf2f(u0) + p1 * bf2f(u1) + p2 * bf2f(u2) + p3 * bf2f(u3);
    }
    for (; e < r1; ++e) {
        int s0 = col[e];
        float p0 = __expf(lrelu(a_src[s0 * 8 + hh] + ad));
        z += p0;
        acc += p0 * bf2f(hb[(long)s0 * 64 + k]);
    }
    out[(long)n * 64 + k] = acc / (z + 1e-16f);
}

// ---------- layer-2 projection (+b1 fused) + attention terms ----------
__global__ __launch_bounds__(256) void proj2_kernel(const float* __restrict__ out1,
                                                    const float* __restrict__ b1,
                                                    const float* __restrict__ W2,
                                                    const float* __restrict__ asrc2_w,
                                                    const float* __restrict__ adst2_w,
                                                    float* __restrict__ h2p,
                                                    float* __restrict__ a_src2,
                                                    float* __restrict__ a_dst2) {
    int gtid = blockIdx.x * blockDim.x + threadIdx.x;
    int n = gtid >> 6;
    int lane = threadIdx.x & 63;
    if (n >= N_NODES) return;
    float v = out1[(long)n * 64 + lane] + b1[lane];
    float part[NC];
    #pragma unroll
    for (int c = 0; c < NC; c++) part[c] = v * W2[lane * NC + c];
    #pragma unroll
    for (int off = 32; off >= 1; off >>= 1)
        #pragma unroll
        for (int c = 0; c < NC; c++) part[c] += __shfl_xor(part[c], off, 64);
    if (lane == 0) {
        float as = 0.f, ad = 0.f;
        #pragma unroll
        for (int c = 0; c < NC; c++) {
            h2p[n * NC + c] = part[c];
            as += part[c] * asrc2_w[c];
            ad += part[c] * adst2_w[c];
        }
        a_src2[n] = as;
        a_dst2[n] = ad;
    }
}

// ---------- layer-2 fused softmax+agg+bias+log_softmax (thread per node) ----------
__global__ void agg2_kernel(const unsigned* __restrict__ rowptr, const int* __restrict__ col,
                            const float* __restrict__ a_src2, const float* __restrict__ a_dst2,
                            const float* __restrict__ h2p, const float* __restrict__ b2,
                            float* __restrict__ y) {
    int n = blockIdx.x * blockDim.x + threadIdx.x;
    if (n >= N_NODES) return;
    float ad = a_dst2[n];
    int r0 = rowptr[n], r1 = rowptr[n + 1];
    float acc[NC] = {};
    float z = 0.f;
    for (int e = r0; e < r1; ++e) {
        int s = col[e];
        float p = __expf(lrelu(a_src2[s] + ad));
        z += p;
        #pragma unroll
        for (int c = 0; c < NC; c++) acc[c] += p * h2p[s * NC + c];
    }
    float inv = 1.f / (z + 1e-16f);
    float l[NC], mx = -3.4e38f;
    #pragma unroll
    for (int c = 0; c < NC; c++) {
        l[c] = acc[c] * inv + b2[c];
        mx = fmaxf(mx, l[c]);
    }
    float ssum = 0.f;
    #pragma unroll
    for (int c = 0; c < NC; c++) ssum += __expf(l[c] - mx);
    float lse = __logf(ssum);
    #pragma unroll
    for (int c = 0; c < NC; c++) y[n * NC + c] = l[c] - mx - lse;
}

extern "C" void kernel_launch(void* const* d_in, const int* in_sizes, int n_in,
                              void* d_out, int out_size, void* d_ws, size_t ws_size,
                              hipStream_t stream) {
    const float* x        = (const float*)d_in[0];
    const int*   ei       = (const int*)d_in[1];
    const float* W1       = (const float*)d_in[2];
    const float* att_src1 = (const float*)d_in[3];
    const float* att_dst1 = (const float*)d_in[4];
    const float* b1       = (const float*)d_in[5];
    const float* W2       = (const float*)d_in[6];
    const float* att_src2 = (const float*)d_in[7];
    const float* att_dst2 = (const float*)d_in[8];
    const float* b2       = (const float*)d_in[9];
    float* y = (float*)d_out;

    // workspace layout
    unsigned short* hb = (unsigned short*)d_ws;           // N*64 bf16
    float* a_src1  = (float*)(hb + (long)N_NODES * 64);   // N*8
    float* a_dst1  = a_src1 + N_NODES * 8;                // N*8
    float* out1    = a_dst1 + N_NODES * 8;                // N*64
    float* h2p     = out1 + (long)N_NODES * 64;           // N*5
    float* a_src2  = h2p + N_NODES * NC;                  // N
    float* a_dst2  = a_src2 + N_NODES;                    // N
    unsigned* deg    = (unsigned*)(a_dst2 + N_NODES);     // N
    unsigned* cursor = deg + N_NODES;                     // N
    unsigned* rowptr = cursor + N_NODES;                  // N+1
    unsigned* bsum   = rowptr + N_NODES + 1;              // 256
    unsigned* boff   = bsum + 256;                        // 256
    int*      col    = (int*)(boff + 256);                // ETOT
    short*    Wp     = (short*)(col + ETOT);              // 147456 shorts

    // ---- CSR build + W pre-pack (per call, graph-safe) ----
    hipMemsetAsync(deg,    0, N_NODES * sizeof(unsigned), stream);
    hipMemsetAsync(cursor, 0, N_NODES * sizeof(unsigned), stream);
    hist_kernel<<<(ETOT + 255) / 256, 256, 0, stream>>>(ei, deg);
    packW_kernel<<<(KB * 4 * 64 + 255) / 256, 256, 0, stream>>>(W1, Wp);
    scan_block_kernel<<<NB_SCAN, 256, 0, stream>>>(deg, rowptr, bsum);
    scan_top_kernel<<<1, 256, 0, stream>>>(bsum, boff);
    scan_add_kernel<<<NB_SCAN, 256, 0, stream>>>(rowptr, boff);
    fill_kernel<<<(ETOT + 255) / 256, 256, 0, stream>>>(ei, rowptr, cursor, col);

    // ---- layer 1 ----
    gemm1_mfma<<<(NTILE + 3) / 4, 256, 0, stream>>>(x, Wp, att_src1, att_dst1, hb, a_src1, a_dst1);
    agg1_kernel<<<(N_NODES + 3) / 4, 256, 0, stream>>>(rowptr, col, a_src1, a_dst1, hb, out1);

    // ---- layer 2 ----
    proj2_kernel<<<(N_NODES * 64 + 255) / 256, 256, 0, stream>>>(out1, b1, W2, att_src2, att_dst2, h2p, a_src2, a_dst2);
    agg2_kernel<<<(N_NODES + 255) / 256, 256, 0, stream>>>(rowptr, col, a_src2, a_dst2, h2p, b2, y);
}

// Round 7
// 382.077 us; speedup vs baseline: 4.0447x; 1.1803x over previous
//
#include <hip/hip_runtime.h>

#define N_NODES 50000
#define N_EDGES 1600000
#define ETOT (N_EDGES + N_NODES)   // 1,650,000 (self-loops appended)
#define F_IN 2304
#define HD 64    // H1*D1
#define H1 8
#define D1 8
#define NC 5
#define NB_SCAN ((N_NODES + 255) / 256)   // 196
#define KB (F_IN / 32)                    // 72 K-blocks
#define NTILE (N_NODES / 16)              // 3125 wave tiles

typedef __attribute__((ext_vector_type(8))) short short8v;
typedef __attribute__((ext_vector_type(4))) float f32x4;

__device__ __forceinline__ float lrelu(float x) { return x > 0.f ? x : 0.2f * x; }

__device__ __forceinline__ unsigned short f2bf(float f) {   // RNE fp32->bf16
    unsigned u = __float_as_uint(f);
    u += 0x7fffu + ((u >> 16) & 1u);
    return (unsigned short)(u >> 16);
}
__device__ __forceinline__ float bf2f(unsigned short u) {
    return __uint_as_float(((unsigned)u) << 16);
}

__device__ __forceinline__ void edge_sd(const int* __restrict__ ei, int e, int& s, int& t) {
    if (e < N_EDGES) { s = ei[e]; t = ei[N_EDGES + e]; }
    else { s = e - N_EDGES; t = s; }
}

// ================= CSR build =================
// hist: count degree AND record each edge's slot (atomic return value)
__global__ void hist_kernel(const int* __restrict__ ei, unsigned* __restrict__ deg,
                            int* __restrict__ epos) {
    int e = blockIdx.x * blockDim.x + threadIdx.x;
    if (e >= ETOT) return;
    int s, t; edge_sd(ei, e, s, t);
    epos[e] = (int)atomicAdd(&deg[t], 1u);
}

__global__ void scan_block_kernel(const unsigned* __restrict__ deg,
                                  unsigned* __restrict__ rowptr,
                                  unsigned* __restrict__ bsum) {
    __shared__ unsigned sm[256];
    int i = blockIdx.x * 256 + threadIdx.x;
    unsigned v = (i < N_NODES) ? deg[i] : 0u;
    sm[threadIdx.x] = v;
    __syncthreads();
    #pragma unroll
    for (int off = 1; off < 256; off <<= 1) {
        unsigned u = (threadIdx.x >= off) ? sm[threadIdx.x - off] : 0u;
        __syncthreads();
        sm[threadIdx.x] += u;
        __syncthreads();
    }
    if (i < N_NODES) rowptr[i] = sm[threadIdx.x] - v;   // exclusive
    if (threadIdx.x == 255) bsum[blockIdx.x] = sm[255];
}

__global__ void scan_top_kernel(unsigned* __restrict__ bsum, unsigned* __restrict__ boff) {
    __shared__ unsigned sm[256];
    int i = threadIdx.x;
    unsigned v = (i < NB_SCAN) ? bsum[i] : 0u;
    sm[i] = v;
    __syncthreads();
    #pragma unroll
    for (int off = 1; off < 256; off <<= 1) {
        unsigned u = (i >= off) ? sm[i - off] : 0u;
        __syncthreads();
        sm[i] += u;
        __syncthreads();
    }
    if (i < NB_SCAN) boff[i] = sm[i] - v;   // exclusive
}

__global__ void scan_add_kernel(unsigned* __restrict__ rowptr, const unsigned* __restrict__ boff) {
    int i = blockIdx.x * 256 + threadIdx.x;
    if (i < N_NODES) rowptr[i] += boff[blockIdx.x];
    if (i == 0) rowptr[N_NODES] = ETOT;
}

// fill: atomic-free scatter using recorded slots
__global__ void fill_kernel(const int* __restrict__ ei, const unsigned* __restrict__ rowptr,
                            const int* __restrict__ epos, int* __restrict__ col) {
    int e = blockIdx.x * blockDim.x + threadIdx.x;
    if (e >= ETOT) return;
    int s, t; edge_sd(ei, e, s, t);
    col[rowptr[t] + epos[e]] = s;
}

// ============ W1 pre-pack into MFMA B-fragment layout (bf16) ============
__global__ void packW_kernel(const float* __restrict__ W, short* __restrict__ Wp) {
    int idx = blockIdx.x * 256 + threadIdx.x;   // (k0*4+cb)*64+lane
    if (idx >= KB * 4 * 64) return;
    int lane = idx & 63;
    int cb = (idx >> 6) & 3;
    int k0 = idx >> 8;
    int colg = cb * 16 + (lane & 15);
    int kbase = k0 * 32 + (lane >> 4) * 8;
    short8v v;
    #pragma unroll
    for (int j = 0; j < 8; j++)
        v[j] = (short)f2bf(W[(kbase + j) * HD + colg]);
    *reinterpret_cast<short8v*>(&Wp[(long)idx * 8]) = v;
}

// ============ layer 1 projection via MFMA + fused attention terms ============
__global__ __launch_bounds__(256) void gemm1_mfma(const float* __restrict__ x,
                                                  const short* __restrict__ Wp,
                                                  const float* __restrict__ asrc_w,
                                                  const float* __restrict__ adst_w,
                                                  unsigned short* __restrict__ hb,
                                                  float* __restrict__ a_src,
                                                  float* __restrict__ a_dst) {
    int wave = threadIdx.x >> 6;
    int lane = threadIdx.x & 63;
    int tile = blockIdx.x * 4 + wave;
    if (tile >= NTILE) return;
    int arow = tile * 16 + (lane & 15);
    const f32x4* xp = reinterpret_cast<const f32x4*>(x + (long)arow * F_IN + (lane >> 4) * 8);
    const short8v* wp = reinterpret_cast<const short8v*>(Wp) + lane;
    f32x4 acc0 = {}, acc1 = {}, acc2 = {}, acc3 = {};
    f32x4 x0 = __builtin_nontemporal_load(xp);
    f32x4 x1 = __builtin_nontemporal_load(xp + 1);
    f32x4 y0 = __builtin_nontemporal_load(xp + 8);
    f32x4 y1 = __builtin_nontemporal_load(xp + 9);
    xp += 16;
    for (int k0 = 0; k0 < KB - 2; k0++) {
        short8v b0 = wp[0 * 64];
        short8v b1 = wp[1 * 64];
        short8v b2 = wp[2 * 64];
        short8v b3 = wp[3 * 64];
        wp += 4 * 64;
        f32x4 z0 = __builtin_nontemporal_load(xp);
        f32x4 z1 = __builtin_nontemporal_load(xp + 1);
        xp += 8;
        short8v af;
        #pragma unroll
        for (int j = 0; j < 4; j++) af[j] = (short)f2bf(x0[j]);
        #pragma unroll
        for (int j = 0; j < 4; j++) af[4 + j] = (short)f2bf(x1[j]);
        acc0 = __builtin_amdgcn_mfma_f32_16x16x32_bf16(af, b0, acc0, 0, 0, 0);
        acc1 = __builtin_amdgcn_mfma_f32_16x16x32_bf16(af, b1, acc1, 0, 0, 0);
        acc2 = __builtin_amdgcn_mfma_f32_16x16x32_bf16(af, b2, acc2, 0, 0, 0);
        acc3 = __builtin_amdgcn_mfma_f32_16x16x32_bf16(af, b3, acc3, 0, 0, 0);
        x0 = y0; x1 = y1; y0 = z0; y1 = z1;
    }
    #pragma unroll
    for (int tb = 0; tb < 2; tb++) {   // last two K-blocks
        short8v b0 = wp[0 * 64];
        short8v b1 = wp[1 * 64];
        short8v b2 = wp[2 * 64];
        short8v b3 = wp[3 * 64];
        wp += 4 * 64;
        short8v af;
        #pragma unroll
        for (int j = 0; j < 4; j++) af[j] = (short)f2bf(tb == 0 ? x0[j] : y0[j]);
        #pragma unroll
        for (int j = 0; j < 4; j++) af[4 + j] = (short)f2bf(tb == 0 ? x1[j] : y1[j]);
        acc0 = __builtin_amdgcn_mfma_f32_16x16x32_bf16(af, b0, acc0, 0, 0, 0);
        acc1 = __builtin_amdgcn_mfma_f32_16x16x32_bf16(af, b1, acc1, 0, 0, 0);
        acc2 = __builtin_amdgcn_mfma_f32_16x16x32_bf16(af, b2, acc2, 0, 0, 0);
        acc3 = __builtin_amdgcn_mfma_f32_16x16x32_bf16(af, b3, acc3, 0, 0, 0);
    }
    // C/D layout: col = cb*16 + (lane&15), row = tile*16 + (lane>>4)*4 + r
    int c0 = lane & 15;
    long rbase = (long)(tile * 16 + (lane >> 4) * 4) * HD;
    #pragma unroll
    for (int r = 0; r < 4; r++) {
        hb[rbase + r * HD + c0]      = f2bf(acc0[r]);
        hb[rbase + r * HD + 16 + c0] = f2bf(acc1[r]);
        hb[rbase + r * HD + 32 + c0] = f2bf(acc2[r]);
        hb[rbase + r * HD + 48 + c0] = f2bf(acc3[r]);
    }
    // fused attention terms
    float wsv[4], wdv[4];
    #pragma unroll
    for (int cb = 0; cb < 4; cb++) {
        wsv[cb] = asrc_w[cb * 16 + c0];
        wdv[cb] = adst_w[cb * 16 + c0];
    }
    int nbase = tile * 16 + (lane >> 4) * 4;
    #pragma unroll
    for (int r = 0; r < 4; r++) {
        float a[4] = {acc0[r], acc1[r], acc2[r], acc3[r]};
        #pragma unroll
        for (int cb = 0; cb < 4; cb++) {
            float vs = a[cb] * wsv[cb];
            float vd = a[cb] * wdv[cb];
            vs += __shfl_xor(vs, 1, 64); vd += __shfl_xor(vd, 1, 64);
            vs += __shfl_xor(vs, 2, 64); vd += __shfl_xor(vd, 2, 64);
            vs += __shfl_xor(vs, 4, 64); vd += __shfl_xor(vd, 4, 64);
            if ((c0 & 7) == 0) {
                int hh = 2 * cb + (c0 >> 3);
                a_src[(nbase + r) * 8 + hh] = vs;
                a_dst[(nbase + r) * 8 + hh] = vd;
            }
        }
    }
}

// ---- layer-1 agg + fused layer-2 projection (+b1) + layer-2 attention terms ----
// wave per node; lane k owns output column k; no out1 materialization
__global__ __launch_bounds__(256) void agg1_proj2_kernel(const unsigned* __restrict__ rowptr,
                                                         const int* __restrict__ col,
                                                         const float* __restrict__ a_src,
                                                         const float* __restrict__ a_dst,
                                                         const unsigned short* __restrict__ hb,
                                                         const float* __restrict__ b1,
                                                         const float* __restrict__ W2,
                                                         const float* __restrict__ asrc2_w,
                                                         const float* __restrict__ adst2_w,
                                                         float* __restrict__ h2p,
                                                         float* __restrict__ a_src2,
                                                         float* __restrict__ a_dst2) {
    int n = blockIdx.x * 4 + (threadIdx.x >> 6);
    if (n >= N_NODES) return;
    int k = threadIdx.x & 63;
    int hh = k >> 3;
    float ad = a_dst[n * 8 + hh];
    int r0 = rowptr[n], r1 = rowptr[n + 1];
    float acc = 0.f, z = 0.f;
    int e = r0;
    for (; e + 3 < r1; e += 4) {   // 4 gathers in flight
        int s0 = col[e], s1 = col[e + 1], s2 = col[e + 2], s3 = col[e + 3];
        float as0 = a_src[s0 * 8 + hh];
        float as1 = a_src[s1 * 8 + hh];
        float as2 = a_src[s2 * 8 + hh];
        float as3 = a_src[s3 * 8 + hh];
        unsigned short u0 = hb[(long)s0 * 64 + k];
        unsigned short u1 = hb[(long)s1 * 64 + k];
        unsigned short u2 = hb[(long)s2 * 64 + k];
        unsigned short u3 = hb[(long)s3 * 64 + k];
        float p0 = __expf(lrelu(as0 + ad));
        float p1 = __expf(lrelu(as1 + ad));
        float p2 = __expf(lrelu(as2 + ad));
        float p3 = __expf(lrelu(as3 + ad));
        z += (p0 + p1) + (p2 + p3);
        acc += p0 * bf2f(u0) + p1 * bf2f(u1) + p2 * bf2f(u2) + p3 * bf2f(u3);
    }
    for (; e < r1; ++e) {
        int s0 = col[e];
        float p0 = __expf(lrelu(a_src[s0 * 8 + hh] + ad));
        z += p0;
        acc += p0 * bf2f(hb[(long)s0 * 64 + k]);
    }
    // fused proj2: v = out1[n][k] + b1[k]; h2 = sum_k v * W2[k][:]
    float v = acc / (z + 1e-16f) + b1[k];
    float part[NC];
    #pragma unroll
    for (int c = 0; c < NC; c++) part[c] = v * W2[k * NC + c];
    #pragma unroll
    for (int off = 32; off >= 1; off >>= 1)
        #pragma unroll
        for (int c = 0; c < NC; c++) part[c] += __shfl_xor(part[c], off, 64);
    if (k == 0) {
        float as = 0.f, ad2 = 0.f;
        f32x4 h0; float h4;
        #pragma unroll
        for (int c = 0; c < NC; c++) {
            as  += part[c] * asrc2_w[c];
            ad2 += part[c] * adst2_w[c];
        }
        h0[0] = part[0]; h0[1] = part[1]; h0[2] = part[2]; h0[3] = part[3];
        h4 = part[4];
        *reinterpret_cast<f32x4*>(&h2p[n * 8]) = h0;
        h2p[n * 8 + 4] = h4;
        h2p[n * 8 + 5] = 0.f; h2p[n * 8 + 6] = 0.f; h2p[n * 8 + 7] = 0.f;
        a_src2[n] = as;
        a_dst2[n] = ad2;
    }
}

// ---------- layer-2 fused softmax+agg+bias+log_softmax (thread per node) ----------
__global__ void agg2_kernel(const unsigned* __restrict__ rowptr, const int* __restrict__ col,
                            const float* __restrict__ a_src2, const float* __restrict__ a_dst2,
                            const float* __restrict__ h2p, const float* __restrict__ b2,
                            float* __restrict__ y) {
    int n = blockIdx.x * blockDim.x + threadIdx.x;
    if (n >= N_NODES) return;
    float ad = a_dst2[n];
    int r0 = rowptr[n], r1 = rowptr[n + 1];
    float acc[NC] = {};
    float z = 0.f;
    for (int e = r0; e < r1; ++e) {
        int s = col[e];
        float p = __expf(lrelu(a_src2[s] + ad));
        z += p;
        const f32x4* hp = reinterpret_cast<const f32x4*>(&h2p[s * 8]);
        f32x4 v0 = hp[0];
        float v4 = h2p[s * 8 + 4];
        acc[0] += p * v0[0]; acc[1] += p * v0[1]; acc[2] += p * v0[2];
        acc[3] += p * v0[3]; acc[4] += p * v4;
    }
    float inv = 1.f / (z + 1e-16f);
    float l[NC], mx = -3.4e38f;
    #pragma unroll
    for (int c = 0; c < NC; c++) {
        l[c] = acc[c] * inv + b2[c];
        mx = fmaxf(mx, l[c]);
    }
    float ssum = 0.f;
    #pragma unroll
    for (int c = 0; c < NC; c++) ssum += __expf(l[c] - mx);
    float lse = __logf(ssum);
    #pragma unroll
    for (int c = 0; c < NC; c++) y[n * NC + c] = l[c] - mx - lse;
}

extern "C" void kernel_launch(void* const* d_in, const int* in_sizes, int n_in,
                              void* d_out, int out_size, void* d_ws, size_t ws_size,
                              hipStream_t stream) {
    const float* x        = (const float*)d_in[0];
    const int*   ei       = (const int*)d_in[1];
    const float* W1       = (const float*)d_in[2];
    const float* att_src1 = (const float*)d_in[3];
    const float* att_dst1 = (const float*)d_in[4];
    const float* b1       = (const float*)d_in[5];
    const float* W2       = (const float*)d_in[6];
    const float* att_src2 = (const float*)d_in[7];
    const float* att_dst2 = (const float*)d_in[8];
    const float* b2       = (const float*)d_in[9];
    float* y = (float*)d_out;

    // workspace layout
    unsigned short* hb = (unsigned short*)d_ws;           // N*64 bf16
    float* a_src1  = (float*)(hb + (long)N_NODES * 64);   // N*8
    float* a_dst1  = a_src1 + N_NODES * 8;                // N*8
    float* h2p     = a_dst1 + N_NODES * 8;                // N*8 (padded NC)
    float* a_src2  = h2p + (long)N_NODES * 8;             // N
    float* a_dst2  = a_src2 + N_NODES;                    // N
    unsigned* deg    = (unsigned*)(a_dst2 + N_NODES);     // N
    unsigned* rowptr = deg + N_NODES;                     // N+1
    unsigned* bsum   = rowptr + N_NODES + 1;              // 256
    unsigned* boff   = bsum + 256;                        // 256
    int*      col    = (int*)(boff + 256);                // ETOT
    int*      epos   = col + ETOT;                        // ETOT
    short*    Wp     = (short*)(epos + ETOT);             // 147456 shorts

    // ---- CSR build + W pre-pack (per call, graph-safe) ----
    hipMemsetAsync(deg, 0, N_NODES * sizeof(unsigned), stream);
    hist_kernel<<<(ETOT + 255) / 256, 256, 0, stream>>>(ei, deg, epos);
    packW_kernel<<<(KB * 4 * 64 + 255) / 256, 256, 0, stream>>>(W1, Wp);
    scan_block_kernel<<<NB_SCAN, 256, 0, stream>>>(deg, rowptr, bsum);
    scan_top_kernel<<<1, 256, 0, stream>>>(bsum, boff);
    scan_add_kernel<<<NB_SCAN, 256, 0, stream>>>(rowptr, boff);
    fill_kernel<<<(ETOT + 255) / 256, 256, 0, stream>>>(ei, rowptr, epos, col);

    // ---- layer 1 (+ fused layer-2 projection & attention terms) ----
    gemm1_mfma<<<(NTILE + 3) / 4, 256, 0, stream>>>(x, Wp, att_src1, att_dst1, hb, a_src1, a_dst1);
    agg1_proj2_kernel<<<(N_NODES + 3) / 4, 256, 0, stream>>>(rowptr, col, a_src1, a_dst1, hb,
                                                             b1, W2, att_src2, att_dst2,
                                                             h2p, a_src2, a_dst2);

    // ---- layer 2 ----
    agg2_kernel<<<(N_NODES + 255) / 256, 256, 0, stream>>>(rowptr, col, a_src2, a_dst2, h2p, b2, y);
}

// Round 8
// 337.319 us; speedup vs baseline: 4.5813x; 1.1327x over previous
//
#include <hip/hip_runtime.h>

#define N_NODES 50000
#define N_EDGES 1600000
#define ETOT (N_EDGES + N_NODES)   // 1,650,000 (self-loops appended)
#define F_IN 2304
#define HD 64    // H1*D1
#define H1 8
#define D1 8
#define NC 5
#define NB_SCAN ((N_NODES + 255) / 256)   // 196
#define KB (F_IN / 32)                    // 72 K-blocks
#define NTILE (N_NODES / 16)              // 3125 wave tiles
#define GEMM_BLOCKS ((NTILE + 3) / 4)     // 782
#define HIST_BLOCKS 2048

typedef __attribute__((ext_vector_type(8))) short short8v;
typedef __attribute__((ext_vector_type(4))) float f32x4;

__device__ __forceinline__ float lrelu(float x) { return x > 0.f ? x : 0.2f * x; }

__device__ __forceinline__ unsigned short f2bf(float f) {   // RNE fp32->bf16
    unsigned u = __float_as_uint(f);
    u += 0x7fffu + ((u >> 16) & 1u);
    return (unsigned short)(u >> 16);
}
__device__ __forceinline__ float bf2f(unsigned short u) {
    return __uint_as_float(((unsigned)u) << 16);
}

__device__ __forceinline__ void edge_sd(const int* __restrict__ ei, int e, int& s, int& t) {
    if (e < N_EDGES) { s = ei[e]; t = ei[N_EDGES + e]; }
    else { s = e - N_EDGES; t = s; }
}

// ============ W1 pre-pack into MFMA B-fragment layout (bf16) ============
__global__ void packW_kernel(const float* __restrict__ W, short* __restrict__ Wp) {
    int idx = blockIdx.x * 256 + threadIdx.x;   // (k0*4+cb)*64+lane
    if (idx >= KB * 4 * 64) return;
    int lane = idx & 63;
    int cb = (idx >> 6) & 3;
    int k0 = idx >> 8;
    int colg = cb * 16 + (lane & 15);
    int kbase = k0 * 32 + (lane >> 4) * 8;
    short8v v;
    #pragma unroll
    for (int j = 0; j < 8; j++)
        v[j] = (short)f2bf(W[(kbase + j) * HD + colg]);
    *reinterpret_cast<short8v*>(&Wp[(long)idx * 8]) = v;
}

// ==== FAT kernel: gemm1 (MFMA + fused layer-1 attention terms)  ||  hist ====
// blocks [0, GEMM_BLOCKS): one wave per 16-row tile, streams x nontemporally
// blocks [GEMM_BLOCKS, +HIST_BLOCKS): grid-stride degree histogram + slot record
__global__ __launch_bounds__(256) void fat_gemm_hist(const float* __restrict__ x,
                                                     const short* __restrict__ Wp,
                                                     const float* __restrict__ asrc_w,
                                                     const float* __restrict__ adst_w,
                                                     unsigned short* __restrict__ hb,
                                                     float* __restrict__ a_src,
                                                     float* __restrict__ a_dst,
                                                     const int* __restrict__ ei,
                                                     unsigned* __restrict__ deg,
                                                     int* __restrict__ epos) {
    if (blockIdx.x >= GEMM_BLOCKS) {
        int b = blockIdx.x - GEMM_BLOCKS;
        for (long e = (long)b * 256 + threadIdx.x; e < ETOT; e += (long)HIST_BLOCKS * 256) {
            int s, t; edge_sd(ei, (int)e, s, t);
            epos[e] = (int)atomicAdd(&deg[t], 1u);
        }
        return;
    }
    int wave = threadIdx.x >> 6;
    int lane = threadIdx.x & 63;
    int tile = blockIdx.x * 4 + wave;
    if (tile >= NTILE) return;
    int arow = tile * 16 + (lane & 15);
    const f32x4* xp = reinterpret_cast<const f32x4*>(x + (long)arow * F_IN + (lane >> 4) * 8);
    const short8v* wp = reinterpret_cast<const short8v*>(Wp) + lane;
    f32x4 acc0 = {}, acc1 = {}, acc2 = {}, acc3 = {};
    f32x4 x0 = __builtin_nontemporal_load(xp);
    f32x4 x1 = __builtin_nontemporal_load(xp + 1);
    f32x4 y0 = __builtin_nontemporal_load(xp + 8);
    f32x4 y1 = __builtin_nontemporal_load(xp + 9);
    xp += 16;
    for (int k0 = 0; k0 < KB - 2; k0++) {
        short8v b0 = wp[0 * 64];
        short8v b1 = wp[1 * 64];
        short8v b2 = wp[2 * 64];
        short8v b3 = wp[3 * 64];
        wp += 4 * 64;
        f32x4 z0 = __builtin_nontemporal_load(xp);
        f32x4 z1 = __builtin_nontemporal_load(xp + 1);
        xp += 8;
        short8v af;
        #pragma unroll
        for (int j = 0; j < 4; j++) af[j] = (short)f2bf(x0[j]);
        #pragma unroll
        for (int j = 0; j < 4; j++) af[4 + j] = (short)f2bf(x1[j]);
        acc0 = __builtin_amdgcn_mfma_f32_16x16x32_bf16(af, b0, acc0, 0, 0, 0);
        acc1 = __builtin_amdgcn_mfma_f32_16x16x32_bf16(af, b1, acc1, 0, 0, 0);
        acc2 = __builtin_amdgcn_mfma_f32_16x16x32_bf16(af, b2, acc2, 0, 0, 0);
        acc3 = __builtin_amdgcn_mfma_f32_16x16x32_bf16(af, b3, acc3, 0, 0, 0);
        x0 = y0; x1 = y1; y0 = z0; y1 = z1;
    }
    #pragma unroll
    for (int tb = 0; tb < 2; tb++) {   // last two K-blocks
        short8v b0 = wp[0 * 64];
        short8v b1 = wp[1 * 64];
        short8v b2 = wp[2 * 64];
        short8v b3 = wp[3 * 64];
        wp += 4 * 64;
        short8v af;
        #pragma unroll
        for (int j = 0; j < 4; j++) af[j] = (short)f2bf(tb == 0 ? x0[j] : y0[j]);
        #pragma unroll
        for (int j = 0; j < 4; j++) af[4 + j] = (short)f2bf(tb == 0 ? x1[j] : y1[j]);
        acc0 = __builtin_amdgcn_mfma_f32_16x16x32_bf16(af, b0, acc0, 0, 0, 0);
        acc1 = __builtin_amdgcn_mfma_f32_16x16x32_bf16(af, b1, acc1, 0, 0, 0);
        acc2 = __builtin_amdgcn_mfma_f32_16x16x32_bf16(af, b2, acc2, 0, 0, 0);
        acc3 = __builtin_amdgcn_mfma_f32_16x16x32_bf16(af, b3, acc3, 0, 0, 0);
    }
    // C/D layout: col = cb*16 + (lane&15), row = tile*16 + (lane>>4)*4 + r
    int c0 = lane & 15;
    long rbase = (long)(tile * 16 + (lane >> 4) * 4) * HD;
    #pragma unroll
    for (int r = 0; r < 4; r++) {
        hb[rbase + r * HD + c0]      = f2bf(acc0[r]);
        hb[rbase + r * HD + 16 + c0] = f2bf(acc1[r]);
        hb[rbase + r * HD + 32 + c0] = f2bf(acc2[r]);
        hb[rbase + r * HD + 48 + c0] = f2bf(acc3[r]);
    }
    // fused attention terms
    float wsv[4], wdv[4];
    #pragma unroll
    for (int cb = 0; cb < 4; cb++) {
        wsv[cb] = asrc_w[cb * 16 + c0];
        wdv[cb] = adst_w[cb * 16 + c0];
    }
    int nbase = tile * 16 + (lane >> 4) * 4;
    #pragma unroll
    for (int r = 0; r < 4; r++) {
        float a[4] = {acc0[r], acc1[r], acc2[r], acc3[r]};
        #pragma unroll
        for (int cb = 0; cb < 4; cb++) {
            float vs = a[cb] * wsv[cb];
            float vd = a[cb] * wdv[cb];
            vs += __shfl_xor(vs, 1, 64); vd += __shfl_xor(vd, 1, 64);
            vs += __shfl_xor(vs, 2, 64); vd += __shfl_xor(vd, 2, 64);
            vs += __shfl_xor(vs, 4, 64); vd += __shfl_xor(vd, 4, 64);
            if ((c0 & 7) == 0) {
                int hh = 2 * cb + (c0 >> 3);
                a_src[(nbase + r) * 8 + hh] = vs;
                a_dst[(nbase + r) * 8 + hh] = vd;
            }
        }
    }
}

// ================= CSR scan =================
__global__ void scan_block_kernel(const unsigned* __restrict__ deg,
                                  unsigned* __restrict__ rowptr,
                                  unsigned* __restrict__ bsum) {
    __shared__ unsigned sm[256];
    int i = blockIdx.x * 256 + threadIdx.x;
    unsigned v = (i < N_NODES) ? deg[i] : 0u;
    sm[threadIdx.x] = v;
    __syncthreads();
    #pragma unroll
    for (int off = 1; off < 256; off <<= 1) {
        unsigned u = (threadIdx.x >= off) ? sm[threadIdx.x - off] : 0u;
        __syncthreads();
        sm[threadIdx.x] += u;
        __syncthreads();
    }
    if (i < N_NODES) rowptr[i] = sm[threadIdx.x] - v;   // exclusive
    if (threadIdx.x == 255) bsum[blockIdx.x] = sm[255];
}

// fused top-scan + add: each block redundantly scans the 196 block sums in LDS
__global__ void scan_addtop_kernel(unsigned* __restrict__ rowptr,
                                   const unsigned* __restrict__ bsum) {
    __shared__ unsigned sm[256];
    int tid = threadIdx.x;
    unsigned v = (tid < NB_SCAN) ? bsum[tid] : 0u;
    sm[tid] = v;
    __syncthreads();
    #pragma unroll
    for (int off = 1; off < 256; off <<= 1) {
        unsigned u = (tid >= off) ? sm[tid - off] : 0u;
        __syncthreads();
        sm[tid] += u;
        __syncthreads();
    }
    unsigned prefix = (blockIdx.x == 0) ? 0u : sm[blockIdx.x - 1];  // inclusive -> exclusive
    int i = blockIdx.x * 256 + tid;
    if (i < N_NODES) rowptr[i] += prefix;
    if (i == 0) rowptr[N_NODES] = ETOT;
}

// fill: atomic-free scatter using recorded slots
__global__ void fill_kernel(const int* __restrict__ ei, const unsigned* __restrict__ rowptr,
                            const int* __restrict__ epos, int* __restrict__ col) {
    int e = blockIdx.x * blockDim.x + threadIdx.x;
    if (e >= ETOT) return;
    int s, t; edge_sd(ei, e, s, t);
    col[rowptr[t] + epos[e]] = s;
}

// ---- layer-1 agg + fused layer-2 projection (+b1) + layer-2 attention terms ----
__global__ __launch_bounds__(256) void agg1_proj2_kernel(const unsigned* __restrict__ rowptr,
                                                         const int* __restrict__ col,
                                                         const float* __restrict__ a_src,
                                                         const float* __restrict__ a_dst,
                                                         const unsigned short* __restrict__ hb,
                                                         const float* __restrict__ b1,
                                                         const float* __restrict__ W2,
                                                         const float* __restrict__ asrc2_w,
                                                         const float* __restrict__ adst2_w,
                                                         float* __restrict__ h2p,
                                                         float* __restrict__ a_src2,
                                                         float* __restrict__ a_dst2) {
    int n = blockIdx.x * 4 + (threadIdx.x >> 6);
    if (n >= N_NODES) return;
    int k = threadIdx.x & 63;
    int hh = k >> 3;
    float ad = a_dst[n * 8 + hh];
    int r0 = rowptr[n], r1 = rowptr[n + 1];
    float acc = 0.f, z = 0.f;
    int e = r0;
    for (; e + 3 < r1; e += 4) {   // 4 gathers in flight
        int s0 = col[e], s1 = col[e + 1], s2 = col[e + 2], s3 = col[e + 3];
        float as0 = a_src[s0 * 8 + hh];
        float as1 = a_src[s1 * 8 + hh];
        float as2 = a_src[s2 * 8 + hh];
        float as3 = a_src[s3 * 8 + hh];
        unsigned short u0 = hb[(long)s0 * 64 + k];
        unsigned short u1 = hb[(long)s1 * 64 + k];
        unsigned short u2 = hb[(long)s2 * 64 + k];
        unsigned short u3 = hb[(long)s3 * 64 + k];
        float p0 = __expf(lrelu(as0 + ad));
        float p1 = __expf(lrelu(as1 + ad));
        float p2 = __expf(lrelu(as2 + ad));
        float p3 = __expf(lrelu(as3 + ad));
        z += (p0 + p1) + (p2 + p3);
        acc += p0 * bf2f(u0) + p1 * bf2f(u1) + p2 * bf2f(u2) + p3 * bf2f(u3);
    }
    for (; e < r1; ++e) {
        int s0 = col[e];
        float p0 = __expf(lrelu(a_src[s0 * 8 + hh] + ad));
        z += p0;
        acc += p0 * bf2f(hb[(long)s0 * 64 + k]);
    }
    // fused proj2: v = out1[n][k] + b1[k]; h2 = sum_k v * W2[k][:]
    float v = acc / (z + 1e-16f) + b1[k];
    float part[NC];
    #pragma unroll
    for (int c = 0; c < NC; c++) part[c] = v * W2[k * NC + c];
    #pragma unroll
    for (int off = 32; off >= 1; off >>= 1)
        #pragma unroll
        for (int c = 0; c < NC; c++) part[c] += __shfl_xor(part[c], off, 64);
    if (k == 0) {
        float as = 0.f, ad2 = 0.f;
        #pragma unroll
        for (int c = 0; c < NC; c++) {
            as  += part[c] * asrc2_w[c];
            ad2 += part[c] * adst2_w[c];
        }
        f32x4 h0;
        h0[0] = part[0]; h0[1] = part[1]; h0[2] = part[2]; h0[3] = part[3];
        *reinterpret_cast<f32x4*>(&h2p[n * 8]) = h0;
        h2p[n * 8 + 4] = part[4];
        h2p[n * 8 + 5] = 0.f; h2p[n * 8 + 6] = 0.f; h2p[n * 8 + 7] = 0.f;
        a_src2[n] = as;
        a_dst2[n] = ad2;
    }
}

// ---------- layer-2 fused softmax+agg+bias+log_softmax (thread per node) ----------
__global__ void agg2_kernel(const unsigned* __restrict__ rowptr, const int* __restrict__ col,
                            const float* __restrict__ a_src2, const float* __restrict__ a_dst2,
                            const float* __restrict__ h2p, const float* __restrict__ b2,
                            float* __restrict__ y) {
    int n = blockIdx.x * blockDim.x + threadIdx.x;
    if (n >= N_NODES) return;
    float ad = a_dst2[n];
    int r0 = rowptr[n], r1 = rowptr[n + 1];
    float acc[NC] = {};
    float z = 0.f;
    int e = r0;
    for (; e + 3 < r1; e += 4) {   // 4 gathers in flight
        int s0 = col[e], s1 = col[e + 1], s2 = col[e + 2], s3 = col[e + 3];
        float as0 = a_src2[s0], as1 = a_src2[s1], as2 = a_src2[s2], as3 = a_src2[s3];
        f32x4 v0 = *reinterpret_cast<const f32x4*>(&h2p[s0 * 8]);
        f32x4 v1 = *reinterpret_cast<const f32x4*>(&h2p[s1 * 8]);
        f32x4 v2 = *reinterpret_cast<const f32x4*>(&h2p[s2 * 8]);
        f32x4 v3 = *reinterpret_cast<const f32x4*>(&h2p[s3 * 8]);
        float w0 = h2p[s0 * 8 + 4], w1 = h2p[s1 * 8 + 4], w2 = h2p[s2 * 8 + 4], w3 = h2p[s3 * 8 + 4];
        float p0 = __expf(lrelu(as0 + ad));
        float p1 = __expf(lrelu(as1 + ad));
        float p2 = __expf(lrelu(as2 + ad));
        float p3 = __expf(lrelu(as3 + ad));
        z += (p0 + p1) + (p2 + p3);
        #pragma unroll
        for (int c = 0; c < 4; c++)
            acc[c] += p0 * v0[c] + p1 * v1[c] + p2 * v2[c] + p3 * v3[c];
        acc[4] += p0 * w0 + p1 * w1 + p2 * w2 + p3 * w3;
    }
    for (; e < r1; ++e) {
        int s = col[e];
        float p = __expf(lrelu(a_src2[s] + ad));
        z += p;
        f32x4 v0 = *reinterpret_cast<const f32x4*>(&h2p[s * 8]);
        float v4 = h2p[s * 8 + 4];
        acc[0] += p * v0[0]; acc[1] += p * v0[1]; acc[2] += p * v0[2];
        acc[3] += p * v0[3]; acc[4] += p * v4;
    }
    float inv = 1.f / (z + 1e-16f);
    float l[NC], mx = -3.4e38f;
    #pragma unroll
    for (int c = 0; c < NC; c++) {
        l[c] = acc[c] * inv + b2[c];
        mx = fmaxf(mx, l[c]);
    }
    float ssum = 0.f;
    #pragma unroll
    for (int c = 0; c < NC; c++) ssum += __expf(l[c] - mx);
    float lse = __logf(ssum);
    #pragma unroll
    for (int c = 0; c < NC; c++) y[n * NC + c] = l[c] - mx - lse;
}

extern "C" void kernel_launch(void* const* d_in, const int* in_sizes, int n_in,
                              void* d_out, int out_size, void* d_ws, size_t ws_size,
                              hipStream_t stream) {
    const float* x        = (const float*)d_in[0];
    const int*   ei       = (const int*)d_in[1];
    const float* W1       = (const float*)d_in[2];
    const float* att_src1 = (const float*)d_in[3];
    const float* att_dst1 = (const float*)d_in[4];
    const float* b1       = (const float*)d_in[5];
    const float* W2       = (const float*)d_in[6];
    const float* att_src2 = (const float*)d_in[7];
    const float* att_dst2 = (const float*)d_in[8];
    const float* b2       = (const float*)d_in[9];
    float* y = (float*)d_out;

    // workspace layout
    unsigned short* hb = (unsigned short*)d_ws;           // N*64 bf16
    float* a_src1  = (float*)(hb + (long)N_NODES * 64);   // N*8
    float* a_dst1  = a_src1 + N_NODES * 8;                // N*8
    float* h2p     = a_dst1 + N_NODES * 8;                // N*8 (padded NC)
    float* a_src2  = h2p + (long)N_NODES * 8;             // N
    float* a_dst2  = a_src2 + N_NODES;                    // N
    unsigned* deg    = (unsigned*)(a_dst2 + N_NODES);     // N
    unsigned* rowptr = deg + N_NODES;                     // N+1
    unsigned* bsum   = rowptr + N_NODES + 1;              // 256
    int*      col    = (int*)(bsum + 256);                // ETOT
    int*      epos   = col + ETOT;                        // ETOT
    short*    Wp     = (short*)(epos + ETOT);             // 147456 shorts

    hipMemsetAsync(deg, 0, N_NODES * sizeof(unsigned), stream);
    packW_kernel<<<(KB * 4 * 64 + 255) / 256, 256, 0, stream>>>(W1, Wp);

    // gemm1 (+fused att1) || hist, one fat launch
    fat_gemm_hist<<<GEMM_BLOCKS + HIST_BLOCKS, 256, 0, stream>>>(
        x, Wp, att_src1, att_dst1, hb, a_src1, a_dst1, ei, deg, epos);

    scan_block_kernel<<<NB_SCAN, 256, 0, stream>>>(deg, rowptr, bsum);
    scan_addtop_kernel<<<NB_SCAN, 256, 0, stream>>>(rowptr, bsum);
    fill_kernel<<<(ETOT + 255) / 256, 256, 0, stream>>>(ei, rowptr, epos, col);

    agg1_proj2_kernel<<<(N_NODES + 3) / 4, 256, 0, stream>>>(rowptr, col, a_src1, a_dst1, hb,
                                                             b1, W2, att_src2, att_dst2,
                                                             h2p, a_src2, a_dst2);
    agg2_kernel<<<(N_NODES + 255) / 256, 256, 0, stream>>>(rowptr, col, a_src2, a_dst2, h2p, b2, y);
}